// Round 1
// baseline (1724.061 us; speedup 1.0000x reference)
//
#include <hip/hip_runtime.h>

#define NM 131072   // mol nodes
#define EM 524288   // mol edges
#define NG 4096     // graphs
#define DM 6        // mol in dim
#define NP 100000   // prot nodes
#define EP 1600000  // prot edges
#define DP 20       // prot in dim
#define HD 64       // hidden

static inline int cdiv(int a, int b){ return (a + b - 1) / b; }

// ---------------- utility ----------------
__global__ void k_fill(float* __restrict__ p, float v, int n){
    int i = blockIdx.x * 256 + threadIdx.x;
    if (i < n) p[i] = v;
}

__global__ void k_deg(const int* __restrict__ dst, float* __restrict__ deg, int E){
    int e = blockIdx.x * 256 + threadIdx.x;
    if (e < E) atomicAdd(&deg[dst[e]], 1.0f);
}

__global__ void k_rsqrt_inplace(float* __restrict__ p, int n){
    int i = blockIdx.x * 256 + threadIdx.x;
    if (i < n) p[i] = rsqrtf(p[i]);   // deg >= 1 always (self-loop)
}

// ---------------- x @ W (small D), W staged in LDS; 4 nodes/block ----------------
template<int D>
__global__ void k_xw(const float* __restrict__ x, const float* __restrict__ W,
                     float* __restrict__ h, int n){
    __shared__ float Ws[D * HD];
    int tid = threadIdx.x;
    for (int k = tid; k < D * HD; k += 256) Ws[k] = W[k];
    __syncthreads();
    int node = blockIdx.x * 4 + (tid >> 6);
    int j = tid & 63;
    if (node < n) {
        float acc = 0.f;
        #pragma unroll
        for (int k = 0; k < D; k++) acc += x[node * D + k] * Ws[k * HD + j];
        h[node * HD + j] = acc;
    }
}

// ---------------- x[n,64] @ W[64,64], rows + W staged in LDS ----------------
__global__ void k_xw64(const float* __restrict__ x, const float* __restrict__ W,
                       float* __restrict__ h, int n){
    __shared__ float Ws[64 * 64];
    __shared__ float Xs[4 * 64];
    int tid = threadIdx.x;
    for (int k = tid; k < 4096; k += 256) Ws[k] = W[k];
    int r = tid >> 6, j = tid & 63;
    int node = blockIdx.x * 4 + r;
    if (node < n) Xs[tid] = x[node * 64 + j];
    __syncthreads();
    if (node < n) {
        float acc = 0.f;
        #pragma unroll
        for (int k = 0; k < 64; k++) acc += Xs[r * 64 + k] * Ws[k * 64 + j];
        h[node * 64 + j] = acc;
    }
}

// ---------------- GCN: init out with self-loop contribution ----------------
__global__ void k_gcn_init(const float* __restrict__ h, const float* __restrict__ dinv,
                           float* __restrict__ out, int n){
    int i = blockIdx.x * 256 + threadIdx.x;
    if (i < n * 64) {
        float d = dinv[i >> 6];
        out[i] = h[i] * d * d;
    }
}

// ---------------- GCN: edge scatter, one wave (64 lanes) per edge ----------------
__global__ void k_gcn_scatter(const int* __restrict__ ei, const float* __restrict__ h,
                              const float* __restrict__ dinv, float* __restrict__ out, int E){
    int t = blockIdx.x * 256 + threadIdx.x;
    if (t >= E * 64) return;
    int e = t >> 6, j = t & 63;
    int s = ei[e], d = ei[E + e];
    float c = dinv[s] * dinv[d];
    atomicAdd(&out[d * 64 + j], h[s * 64 + j] * c);
}

// ---------------- bias + optional relu ----------------
__global__ void k_bias_act(float* __restrict__ out, const float* __restrict__ b,
                           int n64, int do_relu){
    int i = blockIdx.x * 256 + threadIdx.x;
    if (i < n64) {
        float v = out[i] + b[i & 63];
        out[i] = do_relu ? fmaxf(v, 0.f) : v;
    }
}

// ---------------- GAT: per-node attention dots (es = h.a_src, ed = h.a_dst) ----------------
__global__ void k_att(const float* __restrict__ h, const float* __restrict__ as,
                      const float* __restrict__ ad, float* __restrict__ es,
                      float* __restrict__ ed, int n){
    int t = blockIdx.x * 256 + threadIdx.x;
    int node = t >> 6, j = t & 63;
    if (node >= n) return;
    float v = h[node * 64 + j];
    float x = v * as[j], y = v * ad[j];
    #pragma unroll
    for (int off = 32; off > 0; off >>= 1) {
        x += __shfl_down(x, off, 64);
        y += __shfl_down(y, off, 64);
    }
    if (j == 0) { es[node] = x; ed[node] = y; }
}

__device__ __forceinline__ float leaky(float x){ return x > 0.f ? x : 0.2f * x; }

// softmax denom init with self-loop term (softmax shift-invariant; |e| is O(1) here)
__global__ void k_gat_sinit(const float* __restrict__ es, const float* __restrict__ ed,
                            float* __restrict__ s, int n){
    int i = blockIdx.x * 256 + threadIdx.x;
    if (i < n) s[i] = expf(leaky(es[i] + ed[i]));
}

__global__ void k_gat_edge_s(const int* __restrict__ ei, const float* __restrict__ es,
                             const float* __restrict__ ed, float* __restrict__ s, int E){
    int e = blockIdx.x * 256 + threadIdx.x;
    if (e < E) {
        int u = ei[e], v = ei[E + e];
        atomicAdd(&s[v], expf(leaky(es[u] + ed[v])));
    }
}

// out init with self-loop alpha * h
__global__ void k_gat_init(const float* __restrict__ h, const float* __restrict__ es,
                           const float* __restrict__ ed, const float* __restrict__ s,
                           float* __restrict__ out, int n){
    int i = blockIdx.x * 256 + threadIdx.x;
    if (i < n * 64) {
        int node = i >> 6;
        float a = expf(leaky(es[node] + ed[node])) / s[node];
        out[i] = h[i] * a;
    }
}

__global__ void k_gat_scatter(const int* __restrict__ ei, const float* __restrict__ h,
                              const float* __restrict__ es, const float* __restrict__ ed,
                              const float* __restrict__ s, float* __restrict__ out, int E){
    int t = blockIdx.x * 256 + threadIdx.x;
    if (t >= E * 64) return;
    int e = t >> 6, j = t & 63;
    int u = ei[e], v = ei[E + e];
    float a = expf(leaky(es[u] + ed[v])) / s[v];
    atomicAdd(&out[v * 64 + j], h[u * 64 + j] * a);
}

// ---------------- mol pooling: wave per node ----------------
__global__ void k_pool_mol(const float* __restrict__ out, const int* __restrict__ batch,
                           float* __restrict__ gsum, float* __restrict__ gcnt, int n){
    int t = blockIdx.x * 256 + threadIdx.x;
    int node = t >> 6, j = t & 63;
    if (node >= n) return;
    int g = batch[node];
    atomicAdd(&gsum[g * 64 + j], out[node * 64 + j]);
    if (j == 0) atomicAdd(&gcnt[g], 1.0f);
}

// ---------------- prot pooling: 64-thread blocks, strided, block-partial then atomics ----------------
__global__ void k_pool_prot(const float* __restrict__ out, float* __restrict__ psum, int n){
    int j = threadIdx.x;        // 64 threads
    float acc = 0.f;
    for (int i = blockIdx.x; i < n; i += gridDim.x) acc += out[i * 64 + j];
    atomicAdd(&psum[j], acc);
}

// ---------------- fused classifier ----------------
__global__ void k_cls(const float* __restrict__ gsum, const float* __restrict__ gcnt,
                      const float* __restrict__ psum, const float* __restrict__ W1,
                      const float* __restrict__ b1, const float* __restrict__ w2,
                      const float* __restrict__ b2, float* __restrict__ out){
    __shared__ float W1s[128 * 64];
    int tid = threadIdx.x;
    for (int k = tid; k < 128 * 64; k += 256) W1s[k] = W1[k];
    __syncthreads();
    int g = blockIdx.x * 4 + (tid >> 6);
    int j = tid & 63;
    float inv = 1.0f / fmaxf(gcnt[g], 1.0f);
    const float invp = 1.0f / (float)NP;
    float acc = b1[j];
    #pragma unroll 8
    for (int k = 0; k < 64; k++) acc += (gsum[g * 64 + k] * inv) * W1s[k * 64 + j];
    #pragma unroll 8
    for (int k = 0; k < 64; k++) acc += (psum[k] * invp) * W1s[(64 + k) * 64 + j];
    float v = fmaxf(acc, 0.f) * w2[j];
    #pragma unroll
    for (int off = 32; off > 0; off >>= 1) v += __shfl_down(v, off, 64);
    if (j == 0) out[g] = 1.0f / (1.0f + expf(-(v + b2[0])));
}

extern "C" void kernel_launch(void* const* d_in, const int* in_sizes, int n_in,
                              void* d_out, int out_size, void* d_ws, size_t ws_size,
                              hipStream_t stream) {
    const float* mol_x   = (const float*)d_in[0];
    const int*   mol_ei  = (const int*)d_in[1];
    const int*   mol_bat = (const int*)d_in[2];
    const float* prot_x  = (const float*)d_in[3];
    const int*   prot_ei = (const int*)d_in[4];
    const float* gcn_w1  = (const float*)d_in[5];
    const float* gcn_b1  = (const float*)d_in[6];
    const float* gcn_w2  = (const float*)d_in[7];
    const float* gcn_b2  = (const float*)d_in[8];
    const float* gat_w1  = (const float*)d_in[9];
    const float* gat_as1 = (const float*)d_in[10];
    const float* gat_ad1 = (const float*)d_in[11];
    const float* gat_b1  = (const float*)d_in[12];
    const float* gat_w2  = (const float*)d_in[13];
    const float* gat_as2 = (const float*)d_in[14];
    const float* gat_ad2 = (const float*)d_in[15];
    const float* gat_b2  = (const float*)d_in[16];
    const float* cls_w1  = (const float*)d_in[17];
    const float* cls_b1  = (const float*)d_in[18];
    const float* cls_w2  = (const float*)d_in[19];
    const float* cls_b2  = (const float*)d_in[20];
    float* out = (float*)d_out;

    // workspace layout (floats). mol & prot branches reuse bufA/bufB (stream-ordered).
    float* bufA = (float*)d_ws;              // 8388608 : mol_h  / prot_h
    float* bufB = bufA + 8388608;            // 8388608 : mol_out / prot_out
    float* dinv = bufB + 8388608;            // 131072  : mol deg -> dinv
    float* es   = dinv + NM;                 // 100000
    float* ed   = es + NP;                   // 100000
    float* ssum = ed + NP;                   // 100000
    float* gsum = ssum + NP;                 // 262144
    float* gcnt = gsum + NG * 64;            // 4096
    float* psum = gcnt + NG;                 // 64

    // zero pooled accumulators (contiguous)
    hipMemsetAsync(gsum, 0, (size_t)(NG * 64 + NG + 64) * sizeof(float), stream);

    // ---------- mol branch (GCN x2) ----------
    k_fill<<<cdiv(NM,256),256,0,stream>>>(dinv, 1.0f, NM);
    k_deg<<<cdiv(EM,256),256,0,stream>>>(mol_ei + EM, dinv, EM);
    k_rsqrt_inplace<<<cdiv(NM,256),256,0,stream>>>(dinv, NM);

    k_xw<DM><<<cdiv(NM,4),256,0,stream>>>(mol_x, gcn_w1, bufA, NM);
    k_gcn_init<<<cdiv(NM*64,256),256,0,stream>>>(bufA, dinv, bufB, NM);
    k_gcn_scatter<<<cdiv(EM*64,256),256,0,stream>>>(mol_ei, bufA, dinv, bufB, EM);
    k_bias_act<<<cdiv(NM*64,256),256,0,stream>>>(bufB, gcn_b1, NM*64, 1);

    k_xw64<<<cdiv(NM,4),256,0,stream>>>(bufB, gcn_w2, bufA, NM);
    k_gcn_init<<<cdiv(NM*64,256),256,0,stream>>>(bufA, dinv, bufB, NM);
    k_gcn_scatter<<<cdiv(EM*64,256),256,0,stream>>>(mol_ei, bufA, dinv, bufB, EM);
    k_bias_act<<<cdiv(NM*64,256),256,0,stream>>>(bufB, gcn_b2, NM*64, 0);

    k_pool_mol<<<cdiv(NM*64,256),256,0,stream>>>(bufB, mol_bat, gsum, gcnt, NM);

    // ---------- prot branch (GAT x2) ----------
    k_xw<DP><<<cdiv(NP,4),256,0,stream>>>(prot_x, gat_w1, bufA, NP);
    k_att<<<cdiv(NP*64,256),256,0,stream>>>(bufA, gat_as1, gat_ad1, es, ed, NP);
    k_gat_sinit<<<cdiv(NP,256),256,0,stream>>>(es, ed, ssum, NP);
    k_gat_edge_s<<<cdiv(EP,256),256,0,stream>>>(prot_ei, es, ed, ssum, EP);
    k_gat_init<<<cdiv(NP*64,256),256,0,stream>>>(bufA, es, ed, ssum, bufB, NP);
    k_gat_scatter<<<cdiv(EP*64,256),256,0,stream>>>(prot_ei, bufA, es, ed, ssum, bufB, EP);
    k_bias_act<<<cdiv(NP*64,256),256,0,stream>>>(bufB, gat_b1, NP*64, 1);

    k_xw64<<<cdiv(NP,4),256,0,stream>>>(bufB, gat_w2, bufA, NP);
    k_att<<<cdiv(NP*64,256),256,0,stream>>>(bufA, gat_as2, gat_ad2, es, ed, NP);
    k_gat_sinit<<<cdiv(NP,256),256,0,stream>>>(es, ed, ssum, NP);
    k_gat_edge_s<<<cdiv(EP,256),256,0,stream>>>(prot_ei, es, ed, ssum, EP);
    k_gat_init<<<cdiv(NP*64,256),256,0,stream>>>(bufA, es, ed, ssum, bufB, NP);
    k_gat_scatter<<<cdiv(EP*64,256),256,0,stream>>>(prot_ei, bufA, es, ed, ssum, bufB, EP);
    k_bias_act<<<cdiv(NP*64,256),256,0,stream>>>(bufB, gat_b2, NP*64, 0);

    k_pool_prot<<<256,64,0,stream>>>(bufB, psum, NP);

    // ---------- classifier ----------
    k_cls<<<NG/4,256,0,stream>>>(gsum, gcnt, psum, cls_w1, cls_b1, cls_w2, cls_b2, out);
}

// Round 2
// 1141.419 us; speedup vs baseline: 1.5105x; 1.5105x over previous
//
#include <hip/hip_runtime.h>

#define NM 131072   // mol nodes
#define EM 524288   // mol edges
#define NG 4096     // graphs
#define DM 6        // mol in dim
#define NP 100000   // prot nodes
#define EP 1600000  // prot edges
#define DP 20       // prot in dim

static inline int cdiv(int a, int b){ return (a + b - 1) / b; }

__device__ __forceinline__ float leaky(float x){ return x > 0.f ? x : 0.2f * x; }

// ---------------- CSR build: histogram ----------------
__global__ void k_hist(const int* __restrict__ dst, int* __restrict__ cnt, int E){
    int e = blockIdx.x * 256 + threadIdx.x;
    if (e < E) atomicAdd(&cnt[dst[e]], 1);
}

// ---------------- CSR build: 3-kernel inclusive scan ----------------
__global__ void k_scan_reduce(const int* __restrict__ cnt, int* __restrict__ bsum, int n){
    int tid = threadIdx.x;
    int i = blockIdx.x * 512 + tid;
    int v = (i < n) ? cnt[i] : 0;
    #pragma unroll
    for (int off = 32; off > 0; off >>= 1) v += __shfl_down(v, off, 64);
    __shared__ int ws[8];
    if ((tid & 63) == 0) ws[tid >> 6] = v;
    __syncthreads();
    if (tid == 0) {
        int s = 0;
        #pragma unroll
        for (int k = 0; k < 8; k++) s += ws[k];
        bsum[blockIdx.x] = s;
    }
}

// single block of 256: exclusive scan of block sums (nb <= 256)
__global__ void k_scan_bsum(int* __restrict__ bsum, int nb){
    int tid = threadIdx.x, lane = tid & 63, wid = tid >> 6;
    int v0 = (tid < nb) ? bsum[tid] : 0;
    int v = v0;
    #pragma unroll
    for (int off = 1; off < 64; off <<= 1) {
        int t = __shfl_up(v, off, 64);
        if (lane >= off) v += t;
    }
    __shared__ int ws[4];
    if (lane == 63) ws[wid] = v;
    __syncthreads();
    int add = 0;
    for (int k = 0; k < wid; k++) add += ws[k];
    if (tid < nb) bsum[tid] = v + add - v0;   // exclusive
}

// inclusive scan -> rp[i]; rp[n] = E
__global__ void k_scan_final(const int* __restrict__ cnt, const int* __restrict__ bsum,
                             int* __restrict__ rp, int n, int E){
    int tid = threadIdx.x, lane = tid & 63, wid = tid >> 6;
    int i = blockIdx.x * 512 + tid;
    int v0 = (i < n) ? cnt[i] : 0;
    int v = v0;
    #pragma unroll
    for (int off = 1; off < 64; off <<= 1) {
        int t = __shfl_up(v, off, 64);
        if (lane >= off) v += t;
    }
    __shared__ int ws[8];
    if (lane == 63) ws[wid] = v;
    __syncthreads();
    int add = bsum[blockIdx.x];
    for (int k = 0; k < wid; k++) add += ws[k];
    if (i < n) rp[i] = v + add;
    if (i == n - 1) rp[n] = E;
}

// backward-fill scatter: after this, rp[v] = row start, rp[v+1] = row end
__global__ void k_csr_scatter(const int* __restrict__ ei, int* __restrict__ rp,
                              int* __restrict__ col, int E){
    int e = blockIdx.x * 256 + threadIdx.x;
    if (e < E) {
        int u = ei[e], v = ei[E + e];
        int slot = atomicSub(&rp[v], 1) - 1;
        col[slot] = u;
    }
}

// ---------------- x @ W (+ optional fused attention dots) ----------------
template<int D, int ATT>
__global__ void k_xw(const float* __restrict__ x, const float* __restrict__ W,
                     const float* __restrict__ as_, const float* __restrict__ ad_,
                     float* __restrict__ h, float* __restrict__ es, float* __restrict__ ed_,
                     int n){
    __shared__ float Ws[D * 64];
    int tid = threadIdx.x;
    for (int k = tid; k < D * 64; k += 256) Ws[k] = W[k];
    __syncthreads();
    int node = blockIdx.x * 4 + (tid >> 6);
    int j = tid & 63;
    if (node >= n) return;
    float acc = 0.f;
    #pragma unroll
    for (int k = 0; k < D; k++) acc += x[node * D + k] * Ws[k * 64 + j];
    h[node * 64 + j] = acc;
    if (ATT) {
        float xa = acc * as_[j], ya = acc * ad_[j];
        #pragma unroll
        for (int off = 32; off > 0; off >>= 1) {
            xa += __shfl_down(xa, off, 64);
            ya += __shfl_down(ya, off, 64);
        }
        if (j == 0) { es[node] = xa; ed_[node] = ya; }
    }
}

// ---------------- x[n,64] @ W[64,64] (+ optional fused attention dots) ----------------
template<int ATT>
__global__ void k_xw64(const float* __restrict__ x, const float* __restrict__ W,
                       const float* __restrict__ as_, const float* __restrict__ ad_,
                       float* __restrict__ h, float* __restrict__ es, float* __restrict__ ed_,
                       int n){
    __shared__ float Ws[64 * 64];
    __shared__ float Xs[4 * 64];
    int tid = threadIdx.x;
    for (int k = tid; k < 4096; k += 256) Ws[k] = W[k];
    int r = tid >> 6, j = tid & 63;
    int node = blockIdx.x * 4 + r;
    if (node < n) Xs[tid] = x[node * 64 + j];
    __syncthreads();
    if (node >= n) return;
    float acc = 0.f;
    #pragma unroll
    for (int k = 0; k < 64; k++) acc += Xs[r * 64 + k] * Ws[k * 64 + j];
    h[node * 64 + j] = acc;
    if (ATT) {
        float xa = acc * as_[j], ya = acc * ad_[j];
        #pragma unroll
        for (int off = 32; off > 0; off >>= 1) {
            xa += __shfl_down(xa, off, 64);
            ya += __shfl_down(ya, off, 64);
        }
        if (j == 0) { es[node] = xa; ed_[node] = ya; }
    }
}

// ---------------- GCN gather: one wave per dst node, dinv on the fly ----------------
template<int RELU, int POOL>
__global__ void k_gcn_gather(const int* __restrict__ rp, const int* __restrict__ col,
                             const float* __restrict__ h, const float* __restrict__ b,
                             const int* __restrict__ batch,
                             float* __restrict__ out, float* __restrict__ gsum, int n){
    int t = blockIdx.x * 256 + threadIdx.x;
    int node = t >> 6, j = t & 63;
    if (node >= n) return;
    int s0 = rp[node], s1 = rp[node + 1];
    float dd = rsqrtf((float)(s1 - s0 + 1));
    float acc = dd * h[node * 64 + j];
    for (int p = s0; p < s1; p++) {
        int s = col[p];
        float ds = rsqrtf((float)(rp[s + 1] - rp[s] + 1));
        acc += ds * h[s * 64 + j];
    }
    float v = dd * acc + b[j];
    if (RELU) v = fmaxf(v, 0.f);
    if (POOL) atomicAdd(&gsum[batch[node] * 64 + j], v);
    else out[node * 64 + j] = v;
}

// ---------------- GAT gather: fused softmax + aggregate, one wave per dst ----------------
template<int RELU>
__global__ void k_gat_gather(const int* __restrict__ rp, const int* __restrict__ col,
                             const float* __restrict__ h, const float* __restrict__ es,
                             const float* __restrict__ ed_, const float* __restrict__ b,
                             float* __restrict__ out, int n){
    int t = blockIdx.x * 256 + threadIdx.x;
    int node = t >> 6, j = t & 63;
    if (node >= n) return;
    int s0 = rp[node], s1 = rp[node + 1];
    float edv = ed_[node];
    float w = __expf(leaky(es[node] + edv));      // self-loop
    float den = w;
    float num = w * h[node * 64 + j];
    for (int p = s0; p < s1; p++) {
        int u = col[p];
        float wu = __expf(leaky(es[u] + edv));
        num += wu * h[u * 64 + j];
        den += wu;
    }
    float v = num / den + b[j];
    if (RELU) v = fmaxf(v, 0.f);
    out[node * 64 + j] = v;
}

// ---------------- graph-size counts ----------------
__global__ void k_cnt_batch(const int* __restrict__ batch, float* __restrict__ gcnt, int n){
    int i = blockIdx.x * 256 + threadIdx.x;
    if (i < n) atomicAdd(&gcnt[batch[i]], 1.0f);
}

// ---------------- prot pooling: 256 blocks x 64 threads, strided ----------------
__global__ void k_pool_prot(const float* __restrict__ out, float* __restrict__ psum, int n){
    int j = threadIdx.x;
    float acc = 0.f;
    for (int i = blockIdx.x; i < n; i += gridDim.x) acc += out[i * 64 + j];
    atomicAdd(&psum[j], acc);
}

// ---------------- fused classifier ----------------
__global__ void k_cls(const float* __restrict__ gsum, const float* __restrict__ gcnt,
                      const float* __restrict__ psum, const float* __restrict__ W1,
                      const float* __restrict__ b1, const float* __restrict__ w2,
                      const float* __restrict__ b2, float* __restrict__ out){
    __shared__ float W1s[128 * 64];
    int tid = threadIdx.x;
    for (int k = tid; k < 128 * 64; k += 256) W1s[k] = W1[k];
    __syncthreads();
    int g = blockIdx.x * 4 + (tid >> 6);
    int j = tid & 63;
    float inv = 1.0f / fmaxf(gcnt[g], 1.0f);
    const float invp = 1.0f / (float)NP;
    float acc = b1[j];
    #pragma unroll 8
    for (int k = 0; k < 64; k++) acc += (gsum[g * 64 + k] * inv) * W1s[k * 64 + j];
    #pragma unroll 8
    for (int k = 0; k < 64; k++) acc += (psum[k] * invp) * W1s[(64 + k) * 64 + j];
    float v = fmaxf(acc, 0.f) * w2[j];
    #pragma unroll
    for (int off = 32; off > 0; off >>= 1) v += __shfl_down(v, off, 64);
    if (j == 0) out[g] = 1.0f / (1.0f + expf(-(v + b2[0])));
}

extern "C" void kernel_launch(void* const* d_in, const int* in_sizes, int n_in,
                              void* d_out, int out_size, void* d_ws, size_t ws_size,
                              hipStream_t stream) {
    const float* mol_x   = (const float*)d_in[0];
    const int*   mol_ei  = (const int*)d_in[1];
    const int*   mol_bat = (const int*)d_in[2];
    const float* prot_x  = (const float*)d_in[3];
    const int*   prot_ei = (const int*)d_in[4];
    const float* gcn_w1  = (const float*)d_in[5];
    const float* gcn_b1  = (const float*)d_in[6];
    const float* gcn_w2  = (const float*)d_in[7];
    const float* gcn_b2  = (const float*)d_in[8];
    const float* gat_w1  = (const float*)d_in[9];
    const float* gat_as1 = (const float*)d_in[10];
    const float* gat_ad1 = (const float*)d_in[11];
    const float* gat_b1  = (const float*)d_in[12];
    const float* gat_w2  = (const float*)d_in[13];
    const float* gat_as2 = (const float*)d_in[14];
    const float* gat_ad2 = (const float*)d_in[15];
    const float* gat_b2  = (const float*)d_in[16];
    const float* cls_w1  = (const float*)d_in[17];
    const float* cls_b1  = (const float*)d_in[18];
    const float* cls_w2  = (const float*)d_in[19];
    const float* cls_b2  = (const float*)d_in[20];
    float* out = (float*)d_out;

    // ---- workspace layout (fits in the 69.9 MB proven in round 1) ----
    float* ws_f = (float*)d_ws;
    float* bufA = ws_f;                               // 8,388,608 floats
    float* bufB = ws_f + 8388608;                     // 8,388,608 floats
    int*   molRP  = (int*)(ws_f + 16777216);          // 131,073 ints
    int*   molCOL = molRP + 131073;                   // 524,288 ints
    int*   bsum   = molCOL + 524288;                  // 512 ints
    int*   molCNT = molCOL;                           // alias: dead before col written
    // prot-phase aliases (mol branch fully done before these are touched)
    int*   protCOL = (int*)(bufA + 6400000);          // 1,600,000 ints (bufA used [0,6.4M) in prot phase)
    int*   protCNT = protCOL;                         // alias
    int*   protRP  = (int*)(bufB + 6400000);          // 100,001 ints
    float* es   = bufB + 6500032;                     // 100,000
    float* ed_  = bufB + 6600032;                     // 100,000
    float* gsum = bufB + 6700032;                     // 262,144 (survives prot phase: beyond NP*64)
    float* gcnt = gsum + 262144;                      // 4,096
    float* psum = gcnt + 4096;                        // 64

    // ---------- mol CSR ----------
    hipMemsetAsync(molCNT, 0, (size_t)NM * sizeof(int), stream);
    k_hist<<<cdiv(EM,256),256,0,stream>>>(mol_ei + EM, molCNT, EM);
    k_scan_reduce<<<cdiv(NM,512),512,0,stream>>>(molCNT, bsum, NM);
    k_scan_bsum<<<1,256,0,stream>>>(bsum, cdiv(NM,512));
    k_scan_final<<<cdiv(NM,512),512,0,stream>>>(molCNT, bsum, molRP, NM, EM);
    k_csr_scatter<<<cdiv(EM,256),256,0,stream>>>(mol_ei, molRP, molCOL, EM);

    // ---------- mol branch (GCN x2) ----------
    k_xw<DM,0><<<cdiv(NM,4),256,0,stream>>>(mol_x, gcn_w1, nullptr, nullptr, bufA, nullptr, nullptr, NM);
    k_gcn_gather<1,0><<<cdiv(NM*64,256),256,0,stream>>>(molRP, molCOL, bufA, gcn_b1, nullptr, bufB, nullptr, NM);
    k_xw64<0><<<cdiv(NM,4),256,0,stream>>>(bufB, gcn_w2, nullptr, nullptr, bufA, nullptr, nullptr, NM);
    // bufB now dead -> zero pooled accumulators living in its tail
    hipMemsetAsync(gsum, 0, (size_t)(262144 + 4096 + 64) * sizeof(float), stream);
    k_cnt_batch<<<cdiv(NM,256),256,0,stream>>>(mol_bat, gcnt, NM);
    k_gcn_gather<0,1><<<cdiv(NM*64,256),256,0,stream>>>(molRP, molCOL, bufA, gcn_b2, mol_bat, nullptr, gsum, NM);

    // ---------- prot CSR ----------
    hipMemsetAsync(protCNT, 0, (size_t)NP * sizeof(int), stream);
    k_hist<<<cdiv(EP,256),256,0,stream>>>(prot_ei + EP, protCNT, EP);
    k_scan_reduce<<<cdiv(NP,512),512,0,stream>>>(protCNT, bsum, NP);
    k_scan_bsum<<<1,256,0,stream>>>(bsum, cdiv(NP,512));
    k_scan_final<<<cdiv(NP,512),512,0,stream>>>(protCNT, bsum, protRP, NP, EP);
    k_csr_scatter<<<cdiv(EP,256),256,0,stream>>>(prot_ei, protRP, protCOL, EP);

    // ---------- prot branch (GAT x2) ----------
    k_xw<DP,1><<<cdiv(NP,4),256,0,stream>>>(prot_x, gat_w1, gat_as1, gat_ad1, bufA, es, ed_, NP);
    k_gat_gather<1><<<cdiv(NP*64,256),256,0,stream>>>(protRP, protCOL, bufA, es, ed_, gat_b1, bufB, NP);
    k_xw64<1><<<cdiv(NP,4),256,0,stream>>>(bufB, gat_w2, gat_as2, gat_ad2, bufA, es, ed_, NP);
    k_gat_gather<0><<<cdiv(NP*64,256),256,0,stream>>>(protRP, protCOL, bufA, es, ed_, gat_b2, bufB, NP);
    k_pool_prot<<<256,64,0,stream>>>(bufB, psum, NP);

    // ---------- classifier ----------
    k_cls<<<NG/4,256,0,stream>>>(gsum, gcnt, psum, cls_w1, cls_b1, cls_w2, cls_b2, out);
}

// Round 3
// 958.377 us; speedup vs baseline: 1.7989x; 1.1910x over previous
//
#include <hip/hip_runtime.h>

#define NM 131072   // mol nodes
#define EM 524288   // mol edges
#define NG 4096     // graphs
#define DM 6        // mol in dim
#define NP 100000   // prot nodes
#define EP 1600000  // prot edges
#define DP 20       // prot in dim

static inline int cdiv(int a, int b){ return (a + b - 1) / b; }

__device__ __forceinline__ float leaky(float x){ return x > 0.f ? x : 0.2f * x; }

// ---------------- CSR build: histogram ----------------
__global__ void k_hist(const int* __restrict__ dst, int* __restrict__ cnt, int E){
    int e = blockIdx.x * 256 + threadIdx.x;
    if (e < E) atomicAdd(&cnt[dst[e]], 1);
}

// ---------------- CSR build: 3-kernel inclusive scan ----------------
__global__ void k_scan_reduce(const int* __restrict__ cnt, int* __restrict__ bsum, int n){
    int tid = threadIdx.x;
    int i = blockIdx.x * 512 + tid;
    int v = (i < n) ? cnt[i] : 0;
    #pragma unroll
    for (int off = 32; off > 0; off >>= 1) v += __shfl_down(v, off, 64);
    __shared__ int ws[8];
    if ((tid & 63) == 0) ws[tid >> 6] = v;
    __syncthreads();
    if (tid == 0) {
        int s = 0;
        #pragma unroll
        for (int k = 0; k < 8; k++) s += ws[k];
        bsum[blockIdx.x] = s;
    }
}

__global__ void k_scan_bsum(int* __restrict__ bsum, int nb){
    int tid = threadIdx.x, lane = tid & 63, wid = tid >> 6;
    int v0 = (tid < nb) ? bsum[tid] : 0;
    int v = v0;
    #pragma unroll
    for (int off = 1; off < 64; off <<= 1) {
        int t = __shfl_up(v, off, 64);
        if (lane >= off) v += t;
    }
    __shared__ int ws[4];
    if (lane == 63) ws[wid] = v;
    __syncthreads();
    int add = 0;
    for (int k = 0; k < wid; k++) add += ws[k];
    if (tid < nb) bsum[tid] = v + add - v0;   // exclusive
}

__global__ void k_scan_final(const int* __restrict__ cnt, const int* __restrict__ bsum,
                             int* __restrict__ rp, int n, int E){
    int tid = threadIdx.x, lane = tid & 63, wid = tid >> 6;
    int i = blockIdx.x * 512 + tid;
    int v0 = (i < n) ? cnt[i] : 0;
    int v = v0;
    #pragma unroll
    for (int off = 1; off < 64; off <<= 1) {
        int t = __shfl_up(v, off, 64);
        if (lane >= off) v += t;
    }
    __shared__ int ws[8];
    if (lane == 63) ws[wid] = v;
    __syncthreads();
    int add = bsum[blockIdx.x];
    for (int k = 0; k < wid; k++) add += ws[k];
    if (i < n) rp[i] = v + add;
    if (i == n - 1) rp[n] = E;
}

// backward-fill scatter: after this, rp[v] = row start, rp[v+1] = row end
__global__ void k_csr_scatter(const int* __restrict__ ei, int* __restrict__ rp,
                              int* __restrict__ col, int E){
    int e = blockIdx.x * 256 + threadIdx.x;
    if (e < E) {
        int u = ei[e], v = ei[E + e];
        int slot = atomicSub(&rp[v], 1) - 1;
        col[slot] = u;
    }
}

// ---------------- x @ W, small D (+ optional fused attention dots) ----------------
template<int D, int ATT>
__global__ void k_xw(const float* __restrict__ x, const float* __restrict__ W,
                     const float* __restrict__ as_, const float* __restrict__ ad_,
                     float* __restrict__ h, float* __restrict__ es, float* __restrict__ ed_,
                     int n){
    __shared__ float Ws[D * 64];
    int tid = threadIdx.x;
    for (int k = tid; k < D * 64; k += 256) Ws[k] = W[k];
    __syncthreads();
    int node = blockIdx.x * 4 + (tid >> 6);
    int j = tid & 63;
    if (node >= n) return;
    float acc = 0.f;
    #pragma unroll
    for (int k = 0; k < D; k++) acc += x[node * D + k] * Ws[k * 64 + j];
    h[node * 64 + j] = acc;
    if (ATT) {
        float xa = acc * as_[j], ya = acc * ad_[j];
        #pragma unroll
        for (int off = 32; off > 0; off >>= 1) {
            xa += __shfl_down(xa, off, 64);
            ya += __shfl_down(ya, off, 64);
        }
        if (j == 0) { es[node] = xa; ed_[node] = ya; }
    }
}

// ---------------- x[n,64] @ W[64,64]: 16 lanes/node, float4 ----------------
template<int ATT>
__global__ void k_xw64(const float* __restrict__ x, const float* __restrict__ W,
                       const float* __restrict__ as_, const float* __restrict__ ad_,
                       float* __restrict__ h, float* __restrict__ es, float* __restrict__ ed_,
                       int n){
    __shared__ float Ws[64 * 64];
    __shared__ float Xs[16 * 68];     // +4 pad: keeps float4 writes aligned, breaks bank aliasing
    int tid = threadIdx.x;
    {   // stage W (float4)
        for (int k = tid * 4; k < 4096; k += 1024)
            *(float4*)&Ws[k] = *(const float4*)&W[k];
    }
    int nd = tid >> 4, q = tid & 15;
    int node = blockIdx.x * 16 + nd;
    if (node < n) {   // stage X rows
        float4 xv = *(const float4*)&x[node * 64 + (q << 2)];
        *(float4*)&Xs[nd * 68 + (q << 2)] = xv;
    }
    __syncthreads();
    if (node >= n) return;
    float4 acc = {0.f, 0.f, 0.f, 0.f};
    #pragma unroll 8
    for (int k = 0; k < 64; k++) {
        float xk = Xs[nd * 68 + k];
        float4 w4 = *(const float4*)&Ws[(k << 6) + (q << 2)];
        acc.x += xk * w4.x; acc.y += xk * w4.y; acc.z += xk * w4.z; acc.w += xk * w4.w;
    }
    *(float4*)&h[node * 64 + (q << 2)] = acc;
    if (ATT) {
        int f = q << 2;
        float xa = acc.x * as_[f] + acc.y * as_[f + 1] + acc.z * as_[f + 2] + acc.w * as_[f + 3];
        float ya = acc.x * ad_[f] + acc.y * ad_[f + 1] + acc.z * ad_[f + 2] + acc.w * ad_[f + 3];
        #pragma unroll
        for (int m = 1; m < 16; m <<= 1) {
            xa += __shfl_xor(xa, m, 16);
            ya += __shfl_xor(ya, m, 16);
        }
        if (q == 0) { es[node] = xa; ed_[node] = ya; }
    }
}

// ---------------- GCN gather: 1 wave/node, 4 neighbors/iter, float4 rows ----------------
template<int RELU, int POOL>
__global__ void k_gcn_gather(const int* __restrict__ rp, const int* __restrict__ col,
                             const float* __restrict__ h, const float* __restrict__ b,
                             const int* __restrict__ batch,
                             float* __restrict__ out, float* __restrict__ gsum, int n){
    int t = blockIdx.x * 256 + threadIdx.x;
    int node = t >> 6;
    if (node >= n) return;
    int l = t & 63, g = l >> 4, q = l & 15;
    int s0 = rp[node], s1 = rp[node + 1];
    int deg = s1 - s0;
    float dd = rsqrtf((float)(deg + 1));
    float4 num = {0.f, 0.f, 0.f, 0.f};
    int iters = (deg + 4) >> 2;       // ceil((deg+1)/4)
    for (int it = 0; it < iters; it++) {
        int slot = (it << 2) + g - 1; // slot -1 = self-loop
        int u; float w;
        if (slot < 0) { u = node; w = dd; }
        else if (slot < deg) {
            u = col[s0 + slot];
            w = rsqrtf((float)(rp[u + 1] - rp[u] + 1));
        } else { u = node; w = 0.f; }
        float4 hv = *(const float4*)&h[u * 64 + (q << 2)];
        num.x += w * hv.x; num.y += w * hv.y; num.z += w * hv.z; num.w += w * hv.w;
    }
    #pragma unroll
    for (int m = 16; m <= 32; m <<= 1) {
        num.x += __shfl_xor(num.x, m, 64);
        num.y += __shfl_xor(num.y, m, 64);
        num.z += __shfl_xor(num.z, m, 64);
        num.w += __shfl_xor(num.w, m, 64);
    }
    if (g != 0) return;
    int f = q << 2;
    float4 v;
    v.x = dd * num.x + b[f];
    v.y = dd * num.y + b[f + 1];
    v.z = dd * num.z + b[f + 2];
    v.w = dd * num.w + b[f + 3];
    if (RELU) {
        v.x = fmaxf(v.x, 0.f); v.y = fmaxf(v.y, 0.f);
        v.z = fmaxf(v.z, 0.f); v.w = fmaxf(v.w, 0.f);
    }
    if (POOL) {
        int gg = batch[node];
        atomicAdd(&gsum[gg * 64 + f], v.x);
        atomicAdd(&gsum[gg * 64 + f + 1], v.y);
        atomicAdd(&gsum[gg * 64 + f + 2], v.z);
        atomicAdd(&gsum[gg * 64 + f + 3], v.w);
    } else {
        *(float4*)&out[node * 64 + f] = v;
    }
}

// ---------------- GAT gather: fused softmax+aggregate, 4 neighbors/iter ----------------
template<int RELU>
__global__ void k_gat_gather(const int* __restrict__ rp, const int* __restrict__ col,
                             const float* __restrict__ h, const float* __restrict__ es,
                             const float* __restrict__ ed_, const float* __restrict__ b,
                             float* __restrict__ out, int n){
    int t = blockIdx.x * 256 + threadIdx.x;
    int node = t >> 6;
    if (node >= n) return;
    int l = t & 63, g = l >> 4, q = l & 15;
    int s0 = rp[node], s1 = rp[node + 1];
    int deg = s1 - s0;
    float edv = ed_[node];
    float4 num = {0.f, 0.f, 0.f, 0.f};
    float den = 0.f;
    int iters = (deg + 4) >> 2;
    for (int it = 0; it < iters; it++) {
        int slot = (it << 2) + g - 1;
        int u; float w;
        if (slot < 0) { u = node; w = __expf(leaky(es[node] + edv)); }
        else if (slot < deg) {
            u = col[s0 + slot];
            w = __expf(leaky(es[u] + edv));
        } else { u = node; w = 0.f; }
        float4 hv = *(const float4*)&h[u * 64 + (q << 2)];
        num.x += w * hv.x; num.y += w * hv.y; num.z += w * hv.z; num.w += w * hv.w;
        den += w;
    }
    #pragma unroll
    for (int m = 16; m <= 32; m <<= 1) {
        num.x += __shfl_xor(num.x, m, 64);
        num.y += __shfl_xor(num.y, m, 64);
        num.z += __shfl_xor(num.z, m, 64);
        num.w += __shfl_xor(num.w, m, 64);
        den   += __shfl_xor(den,   m, 64);
    }
    if (g != 0) return;
    int f = q << 2;
    float inv = 1.0f / den;
    float4 v;
    v.x = num.x * inv + b[f];
    v.y = num.y * inv + b[f + 1];
    v.z = num.z * inv + b[f + 2];
    v.w = num.w * inv + b[f + 3];
    if (RELU) {
        v.x = fmaxf(v.x, 0.f); v.y = fmaxf(v.y, 0.f);
        v.z = fmaxf(v.z, 0.f); v.w = fmaxf(v.w, 0.f);
    }
    *(float4*)&out[node * 64 + f] = v;
}

// ---------------- graph-size counts ----------------
__global__ void k_cnt_batch(const int* __restrict__ batch, float* __restrict__ gcnt, int n){
    int i = blockIdx.x * 256 + threadIdx.x;
    if (i < n) atomicAdd(&gcnt[batch[i]], 1.0f);
}

// ---------------- prot pooling ----------------
__global__ void k_pool_prot(const float* __restrict__ out, float* __restrict__ psum, int n){
    int j = threadIdx.x;
    float acc = 0.f;
    for (int i = blockIdx.x; i < n; i += gridDim.x) acc += out[i * 64 + j];
    atomicAdd(&psum[j], acc);
}

// ---------------- fused classifier ----------------
__global__ void k_cls(const float* __restrict__ gsum, const float* __restrict__ gcnt,
                      const float* __restrict__ psum, const float* __restrict__ W1,
                      const float* __restrict__ b1, const float* __restrict__ w2,
                      const float* __restrict__ b2, float* __restrict__ out){
    __shared__ float W1s[128 * 64];
    int tid = threadIdx.x;
    for (int k = tid; k < 128 * 64; k += 256) W1s[k] = W1[k];
    __syncthreads();
    int g = blockIdx.x * 4 + (tid >> 6);
    int j = tid & 63;
    float inv = 1.0f / fmaxf(gcnt[g], 1.0f);
    const float invp = 1.0f / (float)NP;
    float acc = b1[j];
    #pragma unroll 8
    for (int k = 0; k < 64; k++) acc += (gsum[g * 64 + k] * inv) * W1s[k * 64 + j];
    #pragma unroll 8
    for (int k = 0; k < 64; k++) acc += (psum[k] * invp) * W1s[(64 + k) * 64 + j];
    float v = fmaxf(acc, 0.f) * w2[j];
    #pragma unroll
    for (int off = 32; off > 0; off >>= 1) v += __shfl_down(v, off, 64);
    if (j == 0) out[g] = 1.0f / (1.0f + expf(-(v + b2[0])));
}

extern "C" void kernel_launch(void* const* d_in, const int* in_sizes, int n_in,
                              void* d_out, int out_size, void* d_ws, size_t ws_size,
                              hipStream_t stream) {
    const float* mol_x   = (const float*)d_in[0];
    const int*   mol_ei  = (const int*)d_in[1];
    const int*   mol_bat = (const int*)d_in[2];
    const float* prot_x  = (const float*)d_in[3];
    const int*   prot_ei = (const int*)d_in[4];
    const float* gcn_w1  = (const float*)d_in[5];
    const float* gcn_b1  = (const float*)d_in[6];
    const float* gcn_w2  = (const float*)d_in[7];
    const float* gcn_b2  = (const float*)d_in[8];
    const float* gat_w1  = (const float*)d_in[9];
    const float* gat_as1 = (const float*)d_in[10];
    const float* gat_ad1 = (const float*)d_in[11];
    const float* gat_b1  = (const float*)d_in[12];
    const float* gat_w2  = (const float*)d_in[13];
    const float* gat_as2 = (const float*)d_in[14];
    const float* gat_ad2 = (const float*)d_in[15];
    const float* gat_b2  = (const float*)d_in[16];
    const float* cls_w1  = (const float*)d_in[17];
    const float* cls_b1  = (const float*)d_in[18];
    const float* cls_w2  = (const float*)d_in[19];
    const float* cls_b2  = (const float*)d_in[20];
    float* out = (float*)d_out;

    // ---- workspace layout (same footprint proven in rounds 1-2) ----
    float* ws_f = (float*)d_ws;
    float* bufA = ws_f;                               // 8,388,608 floats
    float* bufB = ws_f + 8388608;                     // 8,388,608 floats
    int*   molRP  = (int*)(ws_f + 16777216);          // 131,073 ints
    int*   molCOL = molRP + 131073;                   // 524,288 ints
    int*   bsum   = molCOL + 524288;                  // 512 ints
    int*   molCNT = molCOL;                           // alias: dead before col written
    // prot-phase aliases (mol branch fully done before these are touched)
    int*   protCOL = (int*)(bufA + 6400000);          // 1,600,000 ints
    int*   protCNT = protCOL;                         // alias
    int*   protRP  = (int*)(bufB + 6400000);          // 100,001 ints
    float* es   = bufB + 6500032;                     // 100,000
    float* ed_  = bufB + 6600032;                     // 100,000
    float* gsum = bufB + 6700032;                     // 262,144 (beyond NP*64: survives prot phase)
    float* gcnt = gsum + 262144;                      // 4,096
    float* psum = gcnt + 4096;                        // 64

    // ---------- mol CSR ----------
    hipMemsetAsync(molCNT, 0, (size_t)NM * sizeof(int), stream);
    k_hist<<<cdiv(EM,256),256,0,stream>>>(mol_ei + EM, molCNT, EM);
    k_scan_reduce<<<cdiv(NM,512),512,0,stream>>>(molCNT, bsum, NM);
    k_scan_bsum<<<1,256,0,stream>>>(bsum, cdiv(NM,512));
    k_scan_final<<<cdiv(NM,512),512,0,stream>>>(molCNT, bsum, molRP, NM, EM);
    k_csr_scatter<<<cdiv(EM,256),256,0,stream>>>(mol_ei, molRP, molCOL, EM);

    // ---------- mol branch (GCN x2) ----------
    k_xw<DM,0><<<cdiv(NM,4),256,0,stream>>>(mol_x, gcn_w1, nullptr, nullptr, bufA, nullptr, nullptr, NM);
    k_gcn_gather<1,0><<<cdiv(NM*64,256),256,0,stream>>>(molRP, molCOL, bufA, gcn_b1, nullptr, bufB, nullptr, NM);
    k_xw64<0><<<cdiv(NM,16),256,0,stream>>>(bufB, gcn_w2, nullptr, nullptr, bufA, nullptr, nullptr, NM);
    // bufB now dead -> zero pooled accumulators living in its tail
    hipMemsetAsync(gsum, 0, (size_t)(262144 + 4096 + 64) * sizeof(float), stream);
    k_cnt_batch<<<cdiv(NM,256),256,0,stream>>>(mol_bat, gcnt, NM);
    k_gcn_gather<0,1><<<cdiv(NM*64,256),256,0,stream>>>(molRP, molCOL, bufA, gcn_b2, mol_bat, nullptr, gsum, NM);

    // ---------- prot CSR ----------
    hipMemsetAsync(protCNT, 0, (size_t)NP * sizeof(int), stream);
    k_hist<<<cdiv(EP,256),256,0,stream>>>(prot_ei + EP, protCNT, EP);
    k_scan_reduce<<<cdiv(NP,512),512,0,stream>>>(protCNT, bsum, NP);
    k_scan_bsum<<<1,256,0,stream>>>(bsum, cdiv(NP,512));
    k_scan_final<<<cdiv(NP,512),512,0,stream>>>(protCNT, bsum, protRP, NP, EP);
    k_csr_scatter<<<cdiv(EP,256),256,0,stream>>>(prot_ei, protRP, protCOL, EP);

    // ---------- prot branch (GAT x2) ----------
    k_xw<DP,1><<<cdiv(NP,4),256,0,stream>>>(prot_x, gat_w1, gat_as1, gat_ad1, bufA, es, ed_, NP);
    k_gat_gather<1><<<cdiv(NP*64,256),256,0,stream>>>(protRP, protCOL, bufA, es, ed_, gat_b1, bufB, NP);
    k_xw64<1><<<cdiv(NP,16),256,0,stream>>>(bufB, gat_w2, gat_as2, gat_ad2, bufA, es, ed_, NP);
    k_gat_gather<0><<<cdiv(NP*64,256),256,0,stream>>>(protRP, protCOL, bufA, es, ed_, gat_b2, bufB, NP);
    k_pool_prot<<<256,64,0,stream>>>(bufB, psum, NP);

    // ---------- classifier ----------
    k_cls<<<NG/4,256,0,stream>>>(gsum, gcnt, psum, cls_w1, cls_b1, cls_w2, cls_b2, out);
}

// Round 4
// 922.352 us; speedup vs baseline: 1.8692x; 1.0391x over previous
//
#include <hip/hip_runtime.h>

#define NM 131072   // mol nodes
#define EM 524288   // mol edges
#define NG 4096     // graphs
#define DM 6        // mol in dim
#define NP 100000   // prot nodes
#define EP 1600000  // prot edges
#define DP 20       // prot in dim

static inline int cdiv(int a, int b){ return (a + b - 1) / b; }

__device__ __forceinline__ float leaky(float x){ return x > 0.f ? x : 0.2f * x; }

// ---------------- CSR build: histogram ----------------
__global__ void k_hist(const int* __restrict__ dst, int* __restrict__ cnt, int E){
    int e = blockIdx.x * 256 + threadIdx.x;
    if (e < E) atomicAdd(&cnt[dst[e]], 1);
}

// ---------------- CSR build: 3-kernel inclusive scan ----------------
__global__ void k_scan_reduce(const int* __restrict__ cnt, int* __restrict__ bsum, int n){
    int tid = threadIdx.x;
    int i = blockIdx.x * 512 + tid;
    int v = (i < n) ? cnt[i] : 0;
    #pragma unroll
    for (int off = 32; off > 0; off >>= 1) v += __shfl_down(v, off, 64);
    __shared__ int ws[8];
    if ((tid & 63) == 0) ws[tid >> 6] = v;
    __syncthreads();
    if (tid == 0) {
        int s = 0;
        #pragma unroll
        for (int k = 0; k < 8; k++) s += ws[k];
        bsum[blockIdx.x] = s;
    }
}

__global__ void k_scan_bsum(int* __restrict__ bsum, int nb){
    int tid = threadIdx.x, lane = tid & 63, wid = tid >> 6;
    int v0 = (tid < nb) ? bsum[tid] : 0;
    int v = v0;
    #pragma unroll
    for (int off = 1; off < 64; off <<= 1) {
        int t = __shfl_up(v, off, 64);
        if (lane >= off) v += t;
    }
    __shared__ int ws[4];
    if (lane == 63) ws[wid] = v;
    __syncthreads();
    int add = 0;
    for (int k = 0; k < wid; k++) add += ws[k];
    if (tid < nb) bsum[tid] = v + add - v0;   // exclusive
}

__global__ void k_scan_final(const int* __restrict__ cnt, const int* __restrict__ bsum,
                             int* __restrict__ rp, int n, int E){
    int tid = threadIdx.x, lane = tid & 63, wid = tid >> 6;
    int i = blockIdx.x * 512 + tid;
    int v0 = (i < n) ? cnt[i] : 0;
    int v = v0;
    #pragma unroll
    for (int off = 1; off < 64; off <<= 1) {
        int t = __shfl_up(v, off, 64);
        if (lane >= off) v += t;
    }
    __shared__ int ws[8];
    if (lane == 63) ws[wid] = v;
    __syncthreads();
    int add = bsum[blockIdx.x];
    for (int k = 0; k < wid; k++) add += ws[k];
    if (i < n) rp[i] = v + add;
    if (i == n - 1) rp[n] = E;
}

// backward-fill scatter: after this, rp[v] = row start
__global__ void k_csr_scatter(const int* __restrict__ ei, int* __restrict__ rp,
                              int* __restrict__ col, int E){
    int e = blockIdx.x * 256 + threadIdx.x;
    if (e < E) {
        int u = ei[e], v = ei[E + e];
        int slot = atomicSub(&rp[v], 1) - 1;
        col[slot] = u;
    }
}

// ---------------- in-place pack: rp[i] = start | (deg << OBITS) ----------------
// Race-free: 4B stores are word-atomic; masking recovers the offset whether or
// not the neighbor entry was already packed.
template<int OBITS>
__global__ void k_pack(int* __restrict__ rp, int n){
    int i = blockIdx.x * 256 + threadIdx.x;
    if (i < n) {
        const unsigned M = (1u << OBITS) - 1;
        unsigned lo = ((unsigned)rp[i]) & M;
        unsigned hi = ((unsigned)rp[i + 1]) & M;
        rp[i] = (int)(lo | ((hi - lo) << OBITS));
    }
}

// ---------------- GAT edge-weight build: 16 lanes per node over its slots ----------------
template<int OBITS>
__global__ void k_wcsr(const int* __restrict__ rp, const int* __restrict__ col,
                       const float* __restrict__ es, const float* __restrict__ ed_,
                       float* __restrict__ w, int n){
    int t = blockIdx.x * 256 + threadIdx.x;
    int node = t >> 4, q = t & 15;
    unsigned pk = (unsigned)rp[node];
    int s0 = (int)(pk & ((1u << OBITS) - 1));
    int deg = (int)(pk >> OBITS);
    float edv = ed_[node];
    for (int s = q; s < deg; s += 16) {
        int u = col[s0 + s];
        w[s0 + s] = __expf(leaky(es[u] + edv));
    }
}

// ---------------- x @ W, small D (+ optional fused attention dots) ----------------
template<int D, int ATT>
__global__ void k_xw(const float* __restrict__ x, const float* __restrict__ W,
                     const float* __restrict__ as_, const float* __restrict__ ad_,
                     float* __restrict__ h, float* __restrict__ es, float* __restrict__ ed_,
                     int n){
    __shared__ float Ws[D * 64];
    int tid = threadIdx.x;
    for (int k = tid; k < D * 64; k += 256) Ws[k] = W[k];
    __syncthreads();
    int node = blockIdx.x * 4 + (tid >> 6);
    int j = tid & 63;
    if (node >= n) return;
    float acc = 0.f;
    #pragma unroll
    for (int k = 0; k < D; k++) acc += x[node * D + k] * Ws[k * 64 + j];
    h[node * 64 + j] = acc;
    if (ATT) {
        float xa = acc * as_[j], ya = acc * ad_[j];
        #pragma unroll
        for (int off = 32; off > 0; off >>= 1) {
            xa += __shfl_down(xa, off, 64);
            ya += __shfl_down(ya, off, 64);
        }
        if (j == 0) { es[node] = xa; ed_[node] = ya; }
    }
}

// ---------------- x[n,64] @ W[64,64]: 16 lanes/node, float4 ----------------
template<int ATT>
__global__ void k_xw64(const float* __restrict__ x, const float* __restrict__ W,
                       const float* __restrict__ as_, const float* __restrict__ ad_,
                       float* __restrict__ h, float* __restrict__ es, float* __restrict__ ed_,
                       int n){
    __shared__ float Ws[64 * 64];
    __shared__ float Xs[16 * 68];
    int tid = threadIdx.x;
    for (int k = tid * 4; k < 4096; k += 1024)
        *(float4*)&Ws[k] = *(const float4*)&W[k];
    int nd = tid >> 4, q = tid & 15;
    int node = blockIdx.x * 16 + nd;
    if (node < n) {
        float4 xv = *(const float4*)&x[node * 64 + (q << 2)];
        *(float4*)&Xs[nd * 68 + (q << 2)] = xv;
    }
    __syncthreads();
    if (node >= n) return;
    float4 acc = {0.f, 0.f, 0.f, 0.f};
    #pragma unroll 8
    for (int k = 0; k < 64; k++) {
        float xk = Xs[nd * 68 + k];
        float4 w4 = *(const float4*)&Ws[(k << 6) + (q << 2)];
        acc.x += xk * w4.x; acc.y += xk * w4.y; acc.z += xk * w4.z; acc.w += xk * w4.w;
    }
    *(float4*)&h[node * 64 + (q << 2)] = acc;
    if (ATT) {
        int f = q << 2;
        float xa = acc.x * as_[f] + acc.y * as_[f + 1] + acc.z * as_[f + 2] + acc.w * as_[f + 3];
        float ya = acc.x * ad_[f] + acc.y * ad_[f + 1] + acc.z * ad_[f + 2] + acc.w * ad_[f + 3];
        #pragma unroll
        for (int m = 1; m < 16; m <<= 1) {
            xa += __shfl_xor(xa, m, 16);
            ya += __shfl_xor(ya, m, 16);
        }
        if (q == 0) { es[node] = xa; ed_[node] = ya; }
    }
}

// ---------------- GCN gather: packed rp, 8 nbrs in flight, LDS epilogue ----------------
// grid must be exactly n*64/256 (no early returns: __syncthreads inside)
template<int RELU, int POOL, int OBITS>
__global__ void k_gcn_gather(const int* __restrict__ rp, const int* __restrict__ col,
                             const float* __restrict__ h, const float* __restrict__ b,
                             const int* __restrict__ batch,
                             float* __restrict__ out, float* __restrict__ gsum){
    __shared__ float obuf[256];
    int tid = threadIdx.x;
    int node = (blockIdx.x << 2) + (tid >> 6);
    int l = tid & 63, g = l >> 4, q = l & 15;
    unsigned pk = (unsigned)rp[node];
    int s0 = (int)(pk & ((1u << OBITS) - 1));
    int deg = (int)(pk >> OBITS);
    float dd = rsqrtf((float)(deg + 1));
    float4 num = {0.f, 0.f, 0.f, 0.f};
    if (g == 0) {
        float4 hv = *(const float4*)&h[(size_t)node * 64 + (q << 2)];
        num.x = dd * hv.x; num.y = dd * hv.y; num.z = dd * hv.z; num.w = dd * hv.w;
    }
    for (int base = 0; base < deg; base += 8) {
        int sA = base + g, sB = sA + 4;
        int cA = col[s0 + sA], cB = col[s0 + sB];  // +8 slack allocated; clamped below
        int uA = (sA < deg) ? cA : node;
        int uB = (sB < deg) ? cB : node;
        unsigned ka = (unsigned)rp[uA];
        unsigned kb = (unsigned)rp[uB];
        float4 ha = *(const float4*)&h[(size_t)uA * 64 + (q << 2)];
        float4 hb = *(const float4*)&h[(size_t)uB * 64 + (q << 2)];
        float wA = (sA < deg) ? rsqrtf((float)((ka >> OBITS) + 1)) : 0.f;
        float wB = (sB < deg) ? rsqrtf((float)((kb >> OBITS) + 1)) : 0.f;
        num.x += wA * ha.x + wB * hb.x;
        num.y += wA * ha.y + wB * hb.y;
        num.z += wA * ha.z + wB * hb.z;
        num.w += wA * ha.w + wB * hb.w;
    }
    #pragma unroll
    for (int m = 16; m <= 32; m <<= 1) {
        num.x += __shfl_xor(num.x, m, 64);
        num.y += __shfl_xor(num.y, m, 64);
        num.z += __shfl_xor(num.z, m, 64);
        num.w += __shfl_xor(num.w, m, 64);
    }
    if (POOL) {
        if (g == 0) {
            int f = q << 2;
            float4 v;
            v.x = dd * num.x + b[f];     v.y = dd * num.y + b[f + 1];
            v.z = dd * num.z + b[f + 2]; v.w = dd * num.w + b[f + 3];
            if (RELU) { v.x = fmaxf(v.x,0.f); v.y = fmaxf(v.y,0.f); v.z = fmaxf(v.z,0.f); v.w = fmaxf(v.w,0.f); }
            int gg = batch[node];
            atomicAdd(&gsum[gg * 64 + f],     v.x);
            atomicAdd(&gsum[gg * 64 + f + 1], v.y);
            atomicAdd(&gsum[gg * 64 + f + 2], v.z);
            atomicAdd(&gsum[gg * 64 + f + 3], v.w);
        }
    } else {
        if (g == 0) {
            int f = q << 2;
            float4 v;
            v.x = dd * num.x + b[f];     v.y = dd * num.y + b[f + 1];
            v.z = dd * num.z + b[f + 2]; v.w = dd * num.w + b[f + 3];
            if (RELU) { v.x = fmaxf(v.x,0.f); v.y = fmaxf(v.y,0.f); v.z = fmaxf(v.z,0.f); v.w = fmaxf(v.w,0.f); }
            *(float4*)&obuf[(tid >> 6) * 64 + f] = v;
        }
        __syncthreads();
        if (tid < 64) {   // full-wave 1 KiB contiguous store
            float4 v = *(float4*)&obuf[tid << 2];
            *(float4*)&out[(size_t)blockIdx.x * 256 + (tid << 2)] = v;
        }
    }
}

// ---------------- GAT gather: precomputed wcsr, 8 nbrs in flight, LDS epilogue ----------------
template<int RELU, int OBITS>
__global__ void k_gat_gather(const int* __restrict__ rp, const int* __restrict__ col,
                             const float* __restrict__ wcsr, const float* __restrict__ h,
                             const float* __restrict__ es, const float* __restrict__ ed_,
                             const float* __restrict__ b, float* __restrict__ out){
    __shared__ float obuf[256];
    int tid = threadIdx.x;
    int node = (blockIdx.x << 2) + (tid >> 6);
    int l = tid & 63, g = l >> 4, q = l & 15;
    unsigned pk = (unsigned)rp[node];
    int s0 = (int)(pk & ((1u << OBITS) - 1));
    int deg = (int)(pk >> OBITS);
    float4 num = {0.f, 0.f, 0.f, 0.f};
    float den = 0.f;
    if (g == 0) {
        float ws = __expf(leaky(es[node] + ed_[node]));
        float4 hv = *(const float4*)&h[(size_t)node * 64 + (q << 2)];
        num.x = ws * hv.x; num.y = ws * hv.y; num.z = ws * hv.z; num.w = ws * hv.w;
        den = ws;
    }
    for (int base = 0; base < deg; base += 8) {
        int sA = base + g, sB = sA + 4;
        int cA = col[s0 + sA],  cB = col[s0 + sB];
        float fA = wcsr[s0 + sA], fB = wcsr[s0 + sB];
        int uA = (sA < deg) ? cA : node;
        int uB = (sB < deg) ? cB : node;
        float wA = (sA < deg) ? fA : 0.f;
        float wB = (sB < deg) ? fB : 0.f;
        float4 ha = *(const float4*)&h[(size_t)uA * 64 + (q << 2)];
        float4 hb = *(const float4*)&h[(size_t)uB * 64 + (q << 2)];
        num.x += wA * ha.x + wB * hb.x;
        num.y += wA * ha.y + wB * hb.y;
        num.z += wA * ha.z + wB * hb.z;
        num.w += wA * ha.w + wB * hb.w;
        den += wA + wB;
    }
    #pragma unroll
    for (int m = 16; m <= 32; m <<= 1) {
        num.x += __shfl_xor(num.x, m, 64);
        num.y += __shfl_xor(num.y, m, 64);
        num.z += __shfl_xor(num.z, m, 64);
        num.w += __shfl_xor(num.w, m, 64);
        den   += __shfl_xor(den,   m, 64);
    }
    if (g == 0) {
        int f = q << 2;
        float inv = 1.0f / den;
        float4 v;
        v.x = num.x * inv + b[f];     v.y = num.y * inv + b[f + 1];
        v.z = num.z * inv + b[f + 2]; v.w = num.w * inv + b[f + 3];
        if (RELU) { v.x = fmaxf(v.x,0.f); v.y = fmaxf(v.y,0.f); v.z = fmaxf(v.z,0.f); v.w = fmaxf(v.w,0.f); }
        *(float4*)&obuf[(tid >> 6) * 64 + f] = v;
    }
    __syncthreads();
    if (tid < 64) {
        float4 v = *(float4*)&obuf[tid << 2];
        *(float4*)&out[(size_t)blockIdx.x * 256 + (tid << 2)] = v;
    }
}

// ---------------- graph-size counts ----------------
__global__ void k_cnt_batch(const int* __restrict__ batch, float* __restrict__ gcnt, int n){
    int i = blockIdx.x * 256 + threadIdx.x;
    if (i < n) atomicAdd(&gcnt[batch[i]], 1.0f);
}

// ---------------- prot pooling ----------------
__global__ void k_pool_prot(const float* __restrict__ out, float* __restrict__ psum, int n){
    int j = threadIdx.x;
    float acc = 0.f;
    for (int i = blockIdx.x; i < n; i += gridDim.x) acc += out[i * 64 + j];
    atomicAdd(&psum[j], acc);
}

// ---------------- fused classifier ----------------
__global__ void k_cls(const float* __restrict__ gsum, const float* __restrict__ gcnt,
                      const float* __restrict__ psum, const float* __restrict__ W1,
                      const float* __restrict__ b1, const float* __restrict__ w2,
                      const float* __restrict__ b2, float* __restrict__ out){
    __shared__ float W1s[128 * 64];
    int tid = threadIdx.x;
    for (int k = tid; k < 128 * 64; k += 256) W1s[k] = W1[k];
    __syncthreads();
    int g = blockIdx.x * 4 + (tid >> 6);
    int j = tid & 63;
    float inv = 1.0f / fmaxf(gcnt[g], 1.0f);
    const float invp = 1.0f / (float)NP;
    float acc = b1[j];
    #pragma unroll 8
    for (int k = 0; k < 64; k++) acc += (gsum[g * 64 + k] * inv) * W1s[k * 64 + j];
    #pragma unroll 8
    for (int k = 0; k < 64; k++) acc += (psum[k] * invp) * W1s[(64 + k) * 64 + j];
    float v = fmaxf(acc, 0.f) * w2[j];
    #pragma unroll
    for (int off = 32; off > 0; off >>= 1) v += __shfl_down(v, off, 64);
    if (j == 0) out[g] = 1.0f / (1.0f + expf(-(v + b2[0])));
}

extern "C" void kernel_launch(void* const* d_in, const int* in_sizes, int n_in,
                              void* d_out, int out_size, void* d_ws, size_t ws_size,
                              hipStream_t stream) {
    const float* mol_x   = (const float*)d_in[0];
    const int*   mol_ei  = (const int*)d_in[1];
    const int*   mol_bat = (const int*)d_in[2];
    const float* prot_x  = (const float*)d_in[3];
    const int*   prot_ei = (const int*)d_in[4];
    const float* gcn_w1  = (const float*)d_in[5];
    const float* gcn_b1  = (const float*)d_in[6];
    const float* gcn_w2  = (const float*)d_in[7];
    const float* gcn_b2  = (const float*)d_in[8];
    const float* gat_w1  = (const float*)d_in[9];
    const float* gat_as1 = (const float*)d_in[10];
    const float* gat_ad1 = (const float*)d_in[11];
    const float* gat_b1  = (const float*)d_in[12];
    const float* gat_w2  = (const float*)d_in[13];
    const float* gat_as2 = (const float*)d_in[14];
    const float* gat_ad2 = (const float*)d_in[15];
    const float* gat_b2  = (const float*)d_in[16];
    const float* cls_w1  = (const float*)d_in[17];
    const float* cls_b1  = (const float*)d_in[18];
    const float* cls_w2  = (const float*)d_in[19];
    const float* cls_b2  = (const float*)d_in[20];
    float* out = (float*)d_out;

    // ---- workspace layout (≤ 69.73 MB, within the 69.9 MB proven footprint) ----
    float* ws_f = (float*)d_ws;
    float* bufA = ws_f;                               // [0, 8388608)
    float* bufB = ws_f + 8388608;                     // [8388608, 16777216)
    // mol CSR (beyond the two buffers)
    int*   molRP  = (int*)(ws_f + 16777216);          // 131,073
    int*   molCOL = (int*)(ws_f + 16908292);          // 524,288 (+8 slack into bsum)
    int*   bsum   = (int*)(ws_f + 17432584);          // 512
    int*   molCNT = molCOL;
    // prot aliases: bufA tail
    int*   protCOL = (int*)(bufA + 6400000);          // 1,600,000 (+16 slack)
    int*   protCNT = protCOL;
    int*   protRP  = (int*)(bufA + 8000032);          // 100,001
    float* es      = bufA + 8100040;                  // 100,000
    float* ed_     = bufA + 8200040;                  // 100,000
    // prot aliases: bufB tail (prot out uses only [0, 6400000) of bufB)
    float* wcsr    = bufB + 6400000;                  // 1,600,000 (+8 slack)
    float* gsum    = bufB + 8122304;                  // 262,144  (very tail; survives prot phase)
    float* gcnt    = gsum + 262144;                   // 4,096
    float* psum    = gcnt + 4096;                     // 64  -> ends exactly at bufB+8388608

    // ---------- mol CSR ----------
    hipMemsetAsync(molCNT, 0, (size_t)NM * sizeof(int), stream);
    k_hist<<<cdiv(EM,256),256,0,stream>>>(mol_ei + EM, molCNT, EM);
    k_scan_reduce<<<cdiv(NM,512),512,0,stream>>>(molCNT, bsum, NM);
    k_scan_bsum<<<1,256,0,stream>>>(bsum, cdiv(NM,512));
    k_scan_final<<<cdiv(NM,512),512,0,stream>>>(molCNT, bsum, molRP, NM, EM);
    k_csr_scatter<<<cdiv(EM,256),256,0,stream>>>(mol_ei, molRP, molCOL, EM);
    k_pack<20><<<cdiv(NM,256),256,0,stream>>>(molRP, NM);

    // ---------- mol branch (GCN x2) ----------
    k_xw<DM,0><<<cdiv(NM,4),256,0,stream>>>(mol_x, gcn_w1, nullptr, nullptr, bufA, nullptr, nullptr, NM);
    k_gcn_gather<1,0,20><<<NM/4,256,0,stream>>>(molRP, molCOL, bufA, gcn_b1, nullptr, bufB, nullptr);
    k_xw64<0><<<cdiv(NM,16),256,0,stream>>>(bufB, gcn_w2, nullptr, nullptr, bufA, nullptr, nullptr, NM);
    // bufB dead -> zero pooled accumulators living in its tail
    hipMemsetAsync(gsum, 0, (size_t)(262144 + 4096 + 64) * sizeof(float), stream);
    k_cnt_batch<<<cdiv(NM,256),256,0,stream>>>(mol_bat, gcnt, NM);
    k_gcn_gather<0,1,20><<<NM/4,256,0,stream>>>(molRP, molCOL, bufA, gcn_b2, mol_bat, nullptr, gsum);

    // ---------- prot CSR ----------
    hipMemsetAsync(protCNT, 0, (size_t)NP * sizeof(int), stream);
    k_hist<<<cdiv(EP,256),256,0,stream>>>(prot_ei + EP, protCNT, EP);
    k_scan_reduce<<<cdiv(NP,512),512,0,stream>>>(protCNT, bsum, NP);
    k_scan_bsum<<<1,256,0,stream>>>(bsum, cdiv(NP,512));
    k_scan_final<<<cdiv(NP,512),512,0,stream>>>(protCNT, bsum, protRP, NP, EP);
    k_csr_scatter<<<cdiv(EP,256),256,0,stream>>>(prot_ei, protRP, protCOL, EP);
    k_pack<21><<<cdiv(NP,256),256,0,stream>>>(protRP, NP);

    // ---------- prot branch (GAT x2) ----------
    k_xw<DP,1><<<cdiv(NP,4),256,0,stream>>>(prot_x, gat_w1, gat_as1, gat_ad1, bufA, es, ed_, NP);
    k_wcsr<21><<<cdiv(NP*16,256),256,0,stream>>>(protRP, protCOL, es, ed_, wcsr, NP);
    k_gat_gather<1,21><<<NP/4,256,0,stream>>>(protRP, protCOL, wcsr, bufA, es, ed_, gat_b1, bufB);
    k_xw64<1><<<cdiv(NP,16),256,0,stream>>>(bufB, gat_w2, gat_as2, gat_ad2, bufA, es, ed_, NP);
    k_wcsr<21><<<cdiv(NP*16,256),256,0,stream>>>(protRP, protCOL, es, ed_, wcsr, NP);
    k_gat_gather<0,21><<<NP/4,256,0,stream>>>(protRP, protCOL, wcsr, bufA, es, ed_, gat_b2, bufB);
    k_pool_prot<<<256,64,0,stream>>>(bufB, psum, NP);

    // ---------- classifier ----------
    k_cls<<<NG/4,256,0,stream>>>(gsum, gcnt, psum, cls_w1, cls_b1, cls_w2, cls_b2, out);
}

// Round 6
// 835.050 us; speedup vs baseline: 2.0646x; 1.1045x over previous
//
#include <hip/hip_runtime.h>
#include <hip/hip_fp16.h>

#define NM 131072   // mol nodes
#define EM 524288   // mol edges
#define NG 4096     // graphs
#define DM 6        // mol in dim
#define NP 100000   // prot nodes
#define EP 1600000  // prot edges
#define DP 20       // prot in dim

static inline int cdiv(int a, int b){ return (a + b - 1) / b; }

__device__ __forceinline__ float leaky(float x){ return x > 0.f ? x : 0.2f * x; }

union H8 { float4 f4; __half2 h2[4]; };

// ---------------- CSR build: histogram ----------------
__global__ void k_hist(const int* __restrict__ dst, int* __restrict__ cnt, int E){
    int e = blockIdx.x * 256 + threadIdx.x;
    if (e < E) atomicAdd(&cnt[dst[e]], 1);
}

// ---------------- CSR build: 3-kernel inclusive scan ----------------
__global__ void k_scan_reduce(const int* __restrict__ cnt, int* __restrict__ bsum, int n){
    int tid = threadIdx.x;
    int i = blockIdx.x * 512 + tid;
    int v = (i < n) ? cnt[i] : 0;
    #pragma unroll
    for (int off = 32; off > 0; off >>= 1) v += __shfl_down(v, off, 64);
    __shared__ int ws[8];
    if ((tid & 63) == 0) ws[tid >> 6] = v;
    __syncthreads();
    if (tid == 0) {
        int s = 0;
        #pragma unroll
        for (int k = 0; k < 8; k++) s += ws[k];
        bsum[blockIdx.x] = s;
    }
}

__global__ void k_scan_bsum(int* __restrict__ bsum, int nb){
    int tid = threadIdx.x, lane = tid & 63, wid = tid >> 6;
    int v0 = (tid < nb) ? bsum[tid] : 0;
    int v = v0;
    #pragma unroll
    for (int off = 1; off < 64; off <<= 1) {
        int t = __shfl_up(v, off, 64);
        if (lane >= off) v += t;
    }
    __shared__ int ws[4];
    if (lane == 63) ws[wid] = v;
    __syncthreads();
    int add = 0;
    for (int k = 0; k < wid; k++) add += ws[k];
    if (tid < nb) bsum[tid] = v + add - v0;   // exclusive
}

__global__ void k_scan_final(const int* __restrict__ cnt, const int* __restrict__ bsum,
                             int* __restrict__ rp, int n, int E){
    int tid = threadIdx.x, lane = tid & 63, wid = tid >> 6;
    int i = blockIdx.x * 512 + tid;
    int v0 = (i < n) ? cnt[i] : 0;
    int v = v0;
    #pragma unroll
    for (int off = 1; off < 64; off <<= 1) {
        int t = __shfl_up(v, off, 64);
        if (lane >= off) v += t;
    }
    __shared__ int ws[8];
    if (lane == 63) ws[wid] = v;
    __syncthreads();
    int add = bsum[blockIdx.x];
    for (int k = 0; k < wid; k++) add += ws[k];
    if (i < n) rp[i] = v + add;
    if (i == n - 1) rp[n] = E;
}

__global__ void k_csr_scatter(const int* __restrict__ ei, int* __restrict__ rp,
                              int* __restrict__ col, int E){
    int e = blockIdx.x * 256 + threadIdx.x;
    if (e < E) {
        int u = ei[e], v = ei[E + e];
        int slot = atomicSub(&rp[v], 1) - 1;
        col[slot] = u;
    }
}

// in-place pack: rp[i] = start | (deg << OBITS); word-atomic stores make it race-free
template<int OBITS>
__global__ void k_pack(int* __restrict__ rp, int n){
    int i = blockIdx.x * 256 + threadIdx.x;
    if (i < n) {
        const unsigned M = (1u << OBITS) - 1;
        unsigned lo = ((unsigned)rp[i]) & M;
        unsigned hi = ((unsigned)rp[i + 1]) & M;
        rp[i] = (int)(lo | ((hi - lo) << OBITS));
    }
}

template<int OBITS>
__global__ void k_dinv(const int* __restrict__ rp, float* __restrict__ dinv, int n){
    int i = blockIdx.x * 256 + threadIdx.x;
    if (i < n) dinv[i] = rsqrtf((float)(((unsigned)rp[i] >> OBITS) + 1));
}

// GCN per-edge weight, coalesced in CSR order
__global__ void k_wgcn(const int* __restrict__ col, const float* __restrict__ dinv,
                       float* __restrict__ w, int E){
    int p = blockIdx.x * 256 + threadIdx.x;
    if (p < E) w[p] = dinv[col[p]];
}

// GAT per-edge weight: 16 lanes per dst node
template<int OBITS>
__global__ void k_wcsr(const int* __restrict__ rp, const int* __restrict__ col,
                       const float* __restrict__ es, const float* __restrict__ ed_,
                       float* __restrict__ w, int n){
    int t = blockIdx.x * 256 + threadIdx.x;
    int node = t >> 4, q = t & 15;
    unsigned pk = (unsigned)rp[node];
    int s0 = (int)(pk & ((1u << OBITS) - 1));
    int deg = (int)(pk >> OBITS);
    float edv = ed_[node];
    for (int s = q; s < deg; s += 16) {
        int u = col[s0 + s];
        w[s0 + s] = __expf(leaky(es[u] + edv));
    }
}

// fp32 -> fp16 elementwise
__global__ void k_x2h(const float* __restrict__ x, __half* __restrict__ xh, int n){
    int i = blockIdx.x * 256 + threadIdx.x;
    if (i < n) xh[i] = __float2half(x[i]);
}

// va = W @ a_src, vd = W @ a_dst (20-dim each), single tiny block
__global__ void k_va(const float* __restrict__ W, const float* __restrict__ as_,
                     const float* __restrict__ ad_, float* __restrict__ va,
                     float* __restrict__ vd){
    int t = threadIdx.x;
    if (t < 20) {
        float s = 0.f;
        for (int j = 0; j < 64; j++) s += W[t * 64 + j] * as_[j];
        va[t] = s;
    } else if (t >= 32 && t < 52) {
        int k = t - 32;
        float s = 0.f;
        for (int j = 0; j < 64; j++) s += W[k * 64 + j] * ad_[j];
        vd[k] = s;
    }
}

// es[u] = x[u]·va, ed[u] = x[u]·vd
__global__ void k_esed(const float* __restrict__ x, const float* __restrict__ va,
                       const float* __restrict__ vd, float* __restrict__ es,
                       float* __restrict__ ed_, int n){
    int i = blockIdx.x * 256 + threadIdx.x;
    if (i >= n) return;
    float s = 0.f, d = 0.f;
    #pragma unroll
    for (int k = 0; k < 20; k++) { float xv = x[i * 20 + k]; s += xv * va[k]; d += xv * vd[k]; }
    es[i] = s; ed_[i] = d;
}

// ---------------- mol L1 aggregate over raw x (6-dim half rows): 16 groups x 4 lanes ----------------
template<int OBITS>
__global__ void k_gather_x6(const int* __restrict__ rp, const int* __restrict__ col,
                            const float* __restrict__ w, const __half* __restrict__ xh,
                            const float* __restrict__ dinv, float* __restrict__ agg){
    int tid = threadIdx.x;
    int node = (blockIdx.x << 2) + (tid >> 6);
    int l = tid & 63, g = l >> 2, q = l & 3;
    unsigned pk = (unsigned)rp[node];
    int s0 = (int)(pk & ((1u << OBITS) - 1));
    int deg = (int)(pk >> OBITS);
    float dd = dinv[node];
    float2 acc = {0.f, 0.f};
    if (g == 0 && q < 3) {
        float2 f = __half22float2(*(const __half2*)&xh[node * 6 + 2 * q]);
        acc.x = dd * f.x; acc.y = dd * f.y;
    }
    for (int base = 0; base < deg; base += 16) {
        int s = base + g;
        int c = col[s0 + s];        // +16 slack allocated
        float ww = w[s0 + s];
        int u = (s < deg) ? c : node;
        float wv = (s < deg) ? ww : 0.f;
        if (q < 3) {
            float2 f = __half22float2(*(const __half2*)&xh[u * 6 + 2 * q]);
            acc.x += wv * f.x; acc.y += wv * f.y;
        }
    }
    #pragma unroll
    for (int m = 4; m <= 32; m <<= 1) {
        acc.x += __shfl_xor(acc.x, m, 64);
        acc.y += __shfl_xor(acc.y, m, 64);
    }
    if (g == 0 && q < 3)
        *(float2*)&agg[node * 6 + 2 * q] = make_float2(dd * acc.x, dd * acc.y);
}

// ---------------- GAT L1 aggregate over raw x (20-dim half rows): 8 groups x 8 lanes ----------------
template<int OBITS>
__global__ void k_gather_x20(const int* __restrict__ rp, const int* __restrict__ col,
                             const float* __restrict__ w, const __half* __restrict__ xh,
                             const float* __restrict__ es, const float* __restrict__ ed_,
                             float* __restrict__ agg){
    int tid = threadIdx.x;
    int node = (blockIdx.x << 2) + (tid >> 6);
    int l = tid & 63, g = l >> 3, q = l & 7;
    unsigned pk = (unsigned)rp[node];
    int s0 = (int)(pk & ((1u << OBITS) - 1));
    int deg = (int)(pk >> OBITS);
    float2 a0 = {0.f, 0.f}, a1 = {0.f, 0.f};
    float den = 0.f;
    if (g == 0) {
        float ws = __expf(leaky(es[node] + ed_[node]));
        den = ws;
        float2 f0 = __half22float2(*(const __half2*)&xh[node * 20 + 2 * q]);
        a0.x = ws * f0.x; a0.y = ws * f0.y;
        if (q < 2) {
            float2 f1 = __half22float2(*(const __half2*)&xh[node * 20 + 16 + 2 * q]);
            a1.x = ws * f1.x; a1.y = ws * f1.y;
        }
    }
    for (int base = 0; base < deg; base += 8) {
        int s = base + g;
        int c = col[s0 + s]; float ww = w[s0 + s];
        int u = (s < deg) ? c : node;
        float wv = (s < deg) ? ww : 0.f;
        float2 f0 = __half22float2(*(const __half2*)&xh[u * 20 + 2 * q]);
        a0.x += wv * f0.x; a0.y += wv * f0.y;
        if (q < 2) {
            float2 f1 = __half22float2(*(const __half2*)&xh[u * 20 + 16 + 2 * q]);
            a1.x += wv * f1.x; a1.y += wv * f1.y;
        }
        den += wv;
    }
    #pragma unroll
    for (int m = 8; m <= 32; m <<= 1) {
        a0.x += __shfl_xor(a0.x, m, 64); a0.y += __shfl_xor(a0.y, m, 64);
        a1.x += __shfl_xor(a1.x, m, 64); a1.y += __shfl_xor(a1.y, m, 64);
        den  += __shfl_xor(den, m, 64);
    }
    if (g == 0) {
        float inv = 1.f / den;
        *(float2*)&agg[node * 20 + 2 * q] = make_float2(a0.x * inv, a0.y * inv);
        if (q < 2)
            *(float2*)&agg[node * 20 + 16 + 2 * q] = make_float2(a1.x * inv, a1.y * inv);
    }
}

// ---------------- agg[n,D] @ W[D,64] + b (+relu) ----------------
template<int D, int RELU>
__global__ void k_xw_small(const float* __restrict__ x, const float* __restrict__ W,
                           const float* __restrict__ b, float* __restrict__ h, int n){
    __shared__ float Ws[D * 64];
    int tid = threadIdx.x;
    for (int k = tid; k < D * 64; k += 256) Ws[k] = W[k];
    __syncthreads();
    int node = blockIdx.x * 4 + (tid >> 6);
    int j = tid & 63;
    if (node >= n) return;
    float acc = b[j];
    #pragma unroll
    for (int k = 0; k < D; k++) acc += x[node * D + k] * Ws[k * 64 + j];
    if (RELU) acc = fmaxf(acc, 0.f);
    h[(size_t)node * 64 + j] = acc;
}

// ---------------- x[n,64] @ W[64,64] -> half (+ fused attention dots fp32) ----------------
template<int ATT>
__global__ void k_xw64h(const float* __restrict__ x, const float* __restrict__ W,
                        const float* __restrict__ as_, const float* __restrict__ ad_,
                        __half* __restrict__ hout, float* __restrict__ es,
                        float* __restrict__ ed_, int n){
    __shared__ float Ws[64 * 64];
    __shared__ float Xs[16 * 68];
    int tid = threadIdx.x;
    for (int k = tid * 4; k < 4096; k += 1024)
        *(float4*)&Ws[k] = *(const float4*)&W[k];
    int nd = tid >> 4, q = tid & 15;
    int node = blockIdx.x * 16 + nd;
    if (node < n)
        *(float4*)&Xs[nd * 68 + (q << 2)] = *(const float4*)&x[(size_t)node * 64 + (q << 2)];
    __syncthreads();
    if (node >= n) return;
    float4 acc = {0.f, 0.f, 0.f, 0.f};
    #pragma unroll 8
    for (int k = 0; k < 64; k++) {
        float xk = Xs[nd * 68 + k];
        float4 w4 = *(const float4*)&Ws[(k << 6) + (q << 2)];
        acc.x += xk * w4.x; acc.y += xk * w4.y; acc.z += xk * w4.z; acc.w += xk * w4.w;
    }
    union { __half2 h2[2]; float2 f2; } u;
    u.h2[0] = __floats2half2_rn(acc.x, acc.y);
    u.h2[1] = __floats2half2_rn(acc.z, acc.w);
    *(float2*)&hout[(size_t)node * 64 + (q << 2)] = u.f2;
    if (ATT) {
        int f = q << 2;
        float xa = acc.x * as_[f] + acc.y * as_[f + 1] + acc.z * as_[f + 2] + acc.w * as_[f + 3];
        float ya = acc.x * ad_[f] + acc.y * ad_[f + 1] + acc.z * ad_[f + 2] + acc.w * ad_[f + 3];
        #pragma unroll
        for (int m = 1; m < 16; m <<= 1) {
            xa += __shfl_xor(xa, m, 16);
            ya += __shfl_xor(ya, m, 16);
        }
        if (q == 0) { es[node] = xa; ed_[node] = ya; }
    }
}

// ---------------- layer-2 gather over half rows: 8 groups x 8 lanes, 16 B/lane ----------------
template<int GAT, int OBITS>
__global__ void k_gather64h(const int* __restrict__ rp, const int* __restrict__ col,
                            const float* __restrict__ w, const __half* __restrict__ hh,
                            const float* __restrict__ dinv, const float* __restrict__ es,
                            const float* __restrict__ ed_, const float* __restrict__ b,
                            float* __restrict__ out){
    int tid = threadIdx.x;
    int node = (blockIdx.x << 2) + (tid >> 6);
    int l = tid & 63, g = l >> 3, q = l & 7;
    unsigned pk = (unsigned)rp[node];
    int s0 = (int)(pk & ((1u << OBITS) - 1));
    int deg = (int)(pk >> OBITS);
    float acc[8] = {0.f,0.f,0.f,0.f,0.f,0.f,0.f,0.f};
    float den = 0.f;
    float selfw = GAT ? __expf(leaky(es[node] + ed_[node])) : dinv[node];
    if (g == 0) {
        H8 r; r.f4 = *(const float4*)&hh[(size_t)node * 64 + (q << 3)];
        #pragma unroll
        for (int i = 0; i < 4; i++) {
            float2 f = __half22float2(r.h2[i]);
            acc[2*i]     = selfw * f.x;
            acc[2*i + 1] = selfw * f.y;
        }
        den = selfw;
    }
    for (int base = 0; base < deg; base += 8) {
        int s = base + g;
        int c = col[s0 + s]; float ww = w[s0 + s];
        int u = (s < deg) ? c : node;
        float wv = (s < deg) ? ww : 0.f;
        H8 r; r.f4 = *(const float4*)&hh[(size_t)u * 64 + (q << 3)];
        #pragma unroll
        for (int i = 0; i < 4; i++) {
            float2 f = __half22float2(r.h2[i]);
            acc[2*i]     += wv * f.x;
            acc[2*i + 1] += wv * f.y;
        }
        if (GAT) den += wv;
    }
    #pragma unroll
    for (int m = 8; m <= 32; m <<= 1) {
        #pragma unroll
        for (int i = 0; i < 8; i++) acc[i] += __shfl_xor(acc[i], m, 64);
        if (GAT) den += __shfl_xor(den, m, 64);
    }
    if (g == 0) {
        float sc = GAT ? (1.f / den) : selfw;
        int f = q << 3;
        float4 v0, v1;
        v0.x = acc[0]*sc + b[f];     v0.y = acc[1]*sc + b[f+1];
        v0.z = acc[2]*sc + b[f+2];   v0.w = acc[3]*sc + b[f+3];
        v1.x = acc[4]*sc + b[f+4];   v1.y = acc[5]*sc + b[f+5];
        v1.z = acc[6]*sc + b[f+6];   v1.w = acc[7]*sc + b[f+7];
        *(float4*)&out[(size_t)node * 64 + f]     = v0;
        *(float4*)&out[(size_t)node * 64 + f + 4] = v1;
    }
}

// ---------------- mol pooling: segment-based (batch sorted) ----------------
__global__ void k_filli(int* __restrict__ p, int v, int n){
    int i = blockIdx.x * 256 + threadIdx.x;
    if (i < n) p[i] = v;
}
__global__ void k_gstart(const int* __restrict__ batch, int* __restrict__ gstart, int n){
    int i = blockIdx.x * 256 + threadIdx.x;
    if (i < n) atomicMin(&gstart[batch[i]], i);
}
__global__ void k_segpool(const int* __restrict__ gstart, const int* __restrict__ gcnt,
                          const float* __restrict__ x, float* __restrict__ gsum){
    int g = blockIdx.x, j = threadIdx.x;   // 64 threads
    int s = gstart[g], c = gcnt[g];
    float acc = 0.f;
    for (int i = 0; i < c; i++) acc += x[(size_t)(s + i) * 64 + j];
    gsum[g * 64 + j] = acc;
}

// ---------------- prot pooling ----------------
__global__ void k_pool_prot(const float* __restrict__ out, float* __restrict__ psum, int n){
    int j = threadIdx.x;
    float acc = 0.f;
    for (int i = blockIdx.x; i < n; i += gridDim.x) acc += out[i * 64 + j];
    atomicAdd(&psum[j], acc);
}

// ---------------- fused classifier ----------------
__global__ void k_cls(const float* __restrict__ gsum, const int* __restrict__ gcnt,
                      const float* __restrict__ psum, const float* __restrict__ W1,
                      const float* __restrict__ b1, const float* __restrict__ w2,
                      const float* __restrict__ b2, float* __restrict__ out){
    __shared__ float W1s[128 * 64];
    int tid = threadIdx.x;
    for (int k = tid; k < 128 * 64; k += 256) W1s[k] = W1[k];
    __syncthreads();
    int g = blockIdx.x * 4 + (tid >> 6);
    int j = tid & 63;
    float inv = 1.0f / fmaxf((float)gcnt[g], 1.0f);
    const float invp = 1.0f / (float)NP;
    float acc = b1[j];
    #pragma unroll 8
    for (int k = 0; k < 64; k++) acc += (gsum[g * 64 + k] * inv) * W1s[k * 64 + j];
    #pragma unroll 8
    for (int k = 0; k < 64; k++) acc += (psum[k] * invp) * W1s[(64 + k) * 64 + j];
    float v = fmaxf(acc, 0.f) * w2[j];
    #pragma unroll
    for (int off = 32; off > 0; off >>= 1) v += __shfl_down(v, off, 64);
    if (j == 0) out[g] = 1.0f / (1.0f + expf(-(v + b2[0])));
}

extern "C" void kernel_launch(void* const* d_in, const int* in_sizes, int n_in,
                              void* d_out, int out_size, void* d_ws, size_t ws_size,
                              hipStream_t stream) {
    const float* mol_x   = (const float*)d_in[0];
    const int*   mol_ei  = (const int*)d_in[1];
    const int*   mol_bat = (const int*)d_in[2];
    const float* prot_x  = (const float*)d_in[3];
    const int*   prot_ei = (const int*)d_in[4];
    const float* gcn_w1  = (const float*)d_in[5];
    const float* gcn_b1  = (const float*)d_in[6];
    const float* gcn_w2  = (const float*)d_in[7];
    const float* gcn_b2  = (const float*)d_in[8];
    const float* gat_w1  = (const float*)d_in[9];
    const float* gat_as1 = (const float*)d_in[10];
    const float* gat_ad1 = (const float*)d_in[11];
    const float* gat_b1  = (const float*)d_in[12];
    const float* gat_w2  = (const float*)d_in[13];
    const float* gat_as2 = (const float*)d_in[14];
    const float* gat_ad2 = (const float*)d_in[15];
    const float* gat_b2  = (const float*)d_in[16];
    const float* cls_w1  = (const float*)d_in[17];
    const float* cls_b1  = (const float*)d_in[18];
    const float* cls_w2  = (const float*)d_in[19];
    const float* cls_b2  = (const float*)d_in[20];
    float* out = (float*)d_out;

    float* ws_f = (float*)d_ws;

    // ---- persistent tail (beyond both phase regions) ----
    float* T     = ws_f + 16777216;
    float* gsum  = T;                       // 262,144
    int*   gcntI = (int*)(T + 262144);      // 4,096
    float* psum  = T + 266240;              // 64
    int*   gstart= (int*)(T + 266304);      // 4,096
    int*   bsum  = (int*)(T + 270400);      // 512
    float* va    = T + 270912;              // 32
    float* vd    = T + 270944;              // 32

    // ---- mol-phase layout [0, 16777216) ----
    // h2hM is NM*64 halves = 4,194,304 FLOATS -> spans [8388608, 12582912).
    // (Round-5 bug: CSR arrays were placed inside this span.)
    float*  h1     = ws_f;                               // [0, 8388608)
    float*  molout = ws_f;                               // overlay (h1 dead by then)
    __half* h2hM   = (__half*)(ws_f + 8388608);          // [8388608, 12582912)
    int*    molCOL = (int*)(ws_f + 12582912);            // EM+16 -> ends 13,107,216
    int*    molRP  = (int*)(ws_f + 13107216);            // NM+1  -> ends 13,238,289
    float*  dinvM  = ws_f + 13238304;                    // NM    -> ends 13,369,376
    float*  wM     = ws_f + 13369376;                    // EM+16 -> ends 13,893,680
    float*  aggM   = ws_f + 13893680;                    // NM*6  -> ends 14,680,112
    __half* x6h    = (__half*)(ws_f + 14680112);         // NM*6 halves -> ends 15,073,328
    int*    molCNT = molCOL;

    // ---- prot-phase layout [0, 16777216) (mol fully done first) ----
    float*  p       = ws_f;                              // NP*64 = 6,400,000
    float*  protout = ws_f;                              // overlay (p dead by then)
    __half* h2hP    = (__half*)(ws_f + 6400000);         // NP*64 halves -> [6400000, 9600000)
    int*    protCOL = (int*)(ws_f + 9600000);            // EP+16 -> ends 11,200,016
    int*    protRP  = (int*)(ws_f + 11200016);           // NP+1
    float*  es      = ws_f + 11300020;                   // NP
    float*  ed_     = ws_f + 11400020;                   // NP
    float*  wP      = ws_f + 11500020;                   // EP+16 -> ends 13,100,036
    float*  aggP    = ws_f + 13100036;                   // NP*20 -> ends 15,100,036
    __half* x20h    = (__half*)(ws_f + 15100036);        // NP*20 halves -> ends 16,100,036
    int*    protCNT = protCOL;

    // ================= mol branch =================
    hipMemsetAsync(molCNT, 0, (size_t)NM * sizeof(int), stream);
    k_hist<<<cdiv(EM,256),256,0,stream>>>(mol_ei + EM, molCNT, EM);
    k_scan_reduce<<<cdiv(NM,512),512,0,stream>>>(molCNT, bsum, NM);
    k_scan_bsum<<<1,256,0,stream>>>(bsum, cdiv(NM,512));
    k_scan_final<<<cdiv(NM,512),512,0,stream>>>(molCNT, bsum, molRP, NM, EM);
    k_csr_scatter<<<cdiv(EM,256),256,0,stream>>>(mol_ei, molRP, molCOL, EM);
    k_pack<20><<<cdiv(NM,256),256,0,stream>>>(molRP, NM);
    k_dinv<20><<<cdiv(NM,256),256,0,stream>>>(molRP, dinvM, NM);
    k_wgcn<<<cdiv(EM,256),256,0,stream>>>(molCOL, dinvM, wM, EM);
    k_x2h<<<cdiv(NM*DM,256),256,0,stream>>>(mol_x, x6h, NM*DM);
    // L1: aggregate x then transform
    k_gather_x6<20><<<NM/4,256,0,stream>>>(molRP, molCOL, wM, x6h, dinvM, aggM);
    k_xw_small<6,1><<<NM/4,256,0,stream>>>(aggM, gcn_w1, gcn_b1, h1, NM);
    // L2: transform to half, gather, write fp32
    k_xw64h<0><<<NM/16,256,0,stream>>>(h1, gcn_w2, nullptr, nullptr, h2hM, nullptr, nullptr, NM);
    k_gather64h<0,20><<<NM/4,256,0,stream>>>(molRP, molCOL, wM, h2hM, dinvM, nullptr, nullptr, gcn_b2, molout);
    // segment pooling
    k_filli<<<cdiv(NG,256),256,0,stream>>>(gstart, NM, NG);
    hipMemsetAsync(gcntI, 0, (size_t)NG * sizeof(int), stream);
    k_hist<<<cdiv(NM,256),256,0,stream>>>(mol_bat, gcntI, NM);
    k_gstart<<<cdiv(NM,256),256,0,stream>>>(mol_bat, gstart, NM);
    k_segpool<<<NG,64,0,stream>>>(gstart, gcntI, molout, gsum);

    // ================= prot branch =================
    hipMemsetAsync(protCNT, 0, (size_t)NP * sizeof(int), stream);
    k_hist<<<cdiv(EP,256),256,0,stream>>>(prot_ei + EP, protCNT, EP);
    k_scan_reduce<<<cdiv(NP,512),512,0,stream>>>(protCNT, bsum, NP);
    k_scan_bsum<<<1,256,0,stream>>>(bsum, cdiv(NP,512));
    k_scan_final<<<cdiv(NP,512),512,0,stream>>>(protCNT, bsum, protRP, NP, EP);
    k_csr_scatter<<<cdiv(EP,256),256,0,stream>>>(prot_ei, protRP, protCOL, EP);
    k_pack<21><<<cdiv(NP,256),256,0,stream>>>(protRP, NP);
    // L1: es/ed from x directly, aggregate x, then transform
    k_x2h<<<cdiv(NP*DP,256),256,0,stream>>>(prot_x, x20h, NP*DP);
    k_va<<<1,64,0,stream>>>(gat_w1, gat_as1, gat_ad1, va, vd);
    k_esed<<<cdiv(NP,256),256,0,stream>>>(prot_x, va, vd, es, ed_, NP);
    k_wcsr<21><<<cdiv(NP*16,256),256,0,stream>>>(protRP, protCOL, es, ed_, wP, NP);
    k_gather_x20<21><<<NP/4,256,0,stream>>>(protRP, protCOL, wP, x20h, es, ed_, aggP);
    k_xw_small<20,1><<<NP/4,256,0,stream>>>(aggP, gat_w1, gat_b1, p, NP);
    // L2: transform to half (+att dots), gather
    k_xw64h<1><<<NP/16,256,0,stream>>>(p, gat_w2, gat_as2, gat_ad2, h2hP, es, ed_, NP);
    k_wcsr<21><<<cdiv(NP*16,256),256,0,stream>>>(protRP, protCOL, es, ed_, wP, NP);
    k_gather64h<1,21><<<NP/4,256,0,stream>>>(protRP, protCOL, wP, h2hP, nullptr, es, ed_, gat_b2, protout);
    hipMemsetAsync(psum, 0, 64 * sizeof(float), stream);
    k_pool_prot<<<256,64,0,stream>>>(protout, psum, NP);

    // ================= classifier =================
    k_cls<<<NG/4,256,0,stream>>>(gsum, gcntI, psum, cls_w1, cls_b1, cls_w2, cls_b2, out);
}

// Round 7
// 666.909 us; speedup vs baseline: 2.5852x; 1.2521x over previous
//
#include <hip/hip_runtime.h>
#include <hip/hip_fp16.h>

#define NM 131072   // mol nodes
#define EM 524288   // mol edges
#define NG 4096     // graphs
#define DM 6        // mol in dim
#define NP 100000   // prot nodes
#define EP 1600000  // prot edges
#define DP 20       // prot in dim

static inline int cdiv(int a, int b){ return (a + b - 1) / b; }

__device__ __forceinline__ float leaky(float x){ return x > 0.f ? x : 0.2f * x; }

union H8 { float4 f4; __half2 h2[4]; };

// ================= bucketed CSR build =================
// bucket = dst >> 8 (256 nodes/bucket). K_mol=512, K_prot=391.

// coarse histogram: LDS hist per block, one global atomicAdd per block-bucket
template<int CHUNK>
__global__ void k_coarse_hist(const int* __restrict__ dst, int* __restrict__ coarse,
                              int E, int K){
    __shared__ int lh[512];
    int t = threadIdx.x;
    for (int i = t; i < K; i += 256) lh[i] = 0;
    __syncthreads();
    int base = blockIdx.x * CHUNK;
    int end = min(base + CHUNK, E);
    for (int e = base + t; e < end; e += 256)
        atomicAdd(&lh[dst[e] >> 8], 1);
    __syncthreads();
    for (int i = t; i < K; i += 256)
        if (lh[i]) atomicAdd(&coarse[i], lh[i]);
}

// single block of 512: exclusive scan of K<=512 bucket counts -> cstart, cursor
__global__ void k_coarse_scan(const int* __restrict__ coarse, int* __restrict__ cstart,
                              int* __restrict__ cursor, int K, int E){
    int t = threadIdx.x, lane = t & 63, wid = t >> 6;
    int v0 = (t < K) ? coarse[t] : 0;
    int v = v0;
    #pragma unroll
    for (int off = 1; off < 64; off <<= 1) {
        int x = __shfl_up(v, off, 64);
        if (lane >= off) v += x;
    }
    __shared__ int ws[8];
    if (lane == 63) ws[wid] = v;
    __syncthreads();
    int add = 0;
    for (int w = 0; w < wid; w++) add += ws[w];
    int excl = v + add - v0;
    if (t < K) { cstart[t] = excl; cursor[t] = excl; }
    if (t == K - 1) cstart[K] = excl + v0;   // == E
}

// partition edges into bucket regions; payload = (vlow<<24)|u (u < 2^24)
template<int CHUNK, int EPT>
__global__ void k_part(const int* __restrict__ ei, int* __restrict__ cursor,
                       unsigned* __restrict__ buf, int E, int K){
    __shared__ int lh[512];
    __shared__ int lbase[512];
    int t = threadIdx.x;
    for (int i = t; i < K; i += 256) lh[i] = 0;
    __syncthreads();
    int base = blockIdx.x * CHUNK;
    int end = min(base + CHUNK, E);
    unsigned pay[EPT]; int bslot[EPT];
    int cnt = 0;
    for (int e = base + t; e < end; e += 256) {
        int u = ei[e], v = ei[E + e];
        int b = v >> 8;
        int ls = atomicAdd(&lh[b], 1);
        pay[cnt] = ((unsigned)(v & 255) << 24) | (unsigned)u;
        bslot[cnt] = (b << 13) | ls;       // ls < CHUNK <= 4096 (13 bits)
        cnt++;
    }
    __syncthreads();
    for (int i = t; i < K; i += 256)
        lbase[i] = lh[i] ? atomicAdd(&cursor[i], lh[i]) : 0;
    __syncthreads();
    for (int j = 0; j < cnt; j++) {
        int b = bslot[j] >> 13, ls = bslot[j] & 8191;
        buf[lbase[b] + ls] = pay[j];
    }
}

// fine: one block per bucket. LDS degree count -> in-block scan gives rp directly,
// then LDS-cursor scatter of col into the bucket's localized region.
__global__ void k_fine(const unsigned* __restrict__ buf, const int* __restrict__ cstart,
                       int* __restrict__ rp, int* __restrict__ col, int n, int K){
    int k = blockIdx.x, t = threadIdx.x;
    int start = cstart[k], end = cstart[k + 1];
    __shared__ int cnt[256];
    __shared__ int cur[256];
    cnt[t] = 0;
    __syncthreads();
    for (int p = start + t; p < end; p += 256)
        atomicAdd(&cnt[buf[p] >> 24], 1);
    __syncthreads();
    int v0 = cnt[t];
    int lane = t & 63, wid = t >> 6;
    int v = v0;
    #pragma unroll
    for (int off = 1; off < 64; off <<= 1) {
        int x = __shfl_up(v, off, 64);
        if (lane >= off) v += x;
    }
    __shared__ int ws[4];
    if (lane == 63) ws[wid] = v;
    __syncthreads();
    int add = 0;
    for (int w = 0; w < wid; w++) add += ws[w];
    int excl = v + add - v0;
    int ofs = start + excl;
    cur[t] = ofs;
    int idx = (k << 8) + t;
    if (idx <= n) rp[idx] = ofs;           // idx==n lands exactly at E
    if (k == K - 1 && t == 255) rp[n] = end;
    __syncthreads();
    for (int p = start + t; p < end; p += 256) {
        unsigned pk = buf[p];
        int slot = atomicAdd(&cur[pk >> 24], 1);
        col[slot] = (int)(pk & 0xFFFFFFu);
    }
}

// in-place pack: rp[i] = start | (deg << OBITS); word-atomic stores make it race-free
template<int OBITS>
__global__ void k_pack(int* __restrict__ rp, int n){
    int i = blockIdx.x * 256 + threadIdx.x;
    if (i < n) {
        const unsigned M = (1u << OBITS) - 1;
        unsigned lo = ((unsigned)rp[i]) & M;
        unsigned hi = ((unsigned)rp[i + 1]) & M;
        rp[i] = (int)(lo | ((hi - lo) << OBITS));
    }
}

template<int OBITS>
__global__ void k_dinv(const int* __restrict__ rp, float* __restrict__ dinv, int n){
    int i = blockIdx.x * 256 + threadIdx.x;
    if (i < n) dinv[i] = rsqrtf((float)(((unsigned)rp[i] >> OBITS) + 1));
}

// GCN per-edge weight, coalesced in CSR order
__global__ void k_wgcn(const int* __restrict__ col, const float* __restrict__ dinv,
                       float* __restrict__ w, int E){
    int p = blockIdx.x * 256 + threadIdx.x;
    if (p < E) w[p] = dinv[col[p]];
}

// GAT per-edge weight: 16 lanes per dst node
template<int OBITS>
__global__ void k_wcsr(const int* __restrict__ rp, const int* __restrict__ col,
                       const float* __restrict__ es, const float* __restrict__ ed_,
                       float* __restrict__ w, int n){
    int t = blockIdx.x * 256 + threadIdx.x;
    int node = t >> 4, q = t & 15;
    unsigned pk = (unsigned)rp[node];
    int s0 = (int)(pk & ((1u << OBITS) - 1));
    int deg = (int)(pk >> OBITS);
    float edv = ed_[node];
    for (int s = q; s < deg; s += 16) {
        int u = col[s0 + s];
        w[s0 + s] = __expf(leaky(es[u] + edv));
    }
}

// fp32 -> fp16 elementwise
__global__ void k_x2h(const float* __restrict__ x, __half* __restrict__ xh, int n){
    int i = blockIdx.x * 256 + threadIdx.x;
    if (i < n) xh[i] = __float2half(x[i]);
}

// va = W @ a_src, vd = W @ a_dst (20-dim each), single tiny block
__global__ void k_va(const float* __restrict__ W, const float* __restrict__ as_,
                     const float* __restrict__ ad_, float* __restrict__ va,
                     float* __restrict__ vd){
    int t = threadIdx.x;
    if (t < 20) {
        float s = 0.f;
        for (int j = 0; j < 64; j++) s += W[t * 64 + j] * as_[j];
        va[t] = s;
    } else if (t >= 32 && t < 52) {
        int k = t - 32;
        float s = 0.f;
        for (int j = 0; j < 64; j++) s += W[k * 64 + j] * ad_[j];
        vd[k] = s;
    }
}

// es[u] = x[u]·va, ed[u] = x[u]·vd
__global__ void k_esed(const float* __restrict__ x, const float* __restrict__ va,
                       const float* __restrict__ vd, float* __restrict__ es,
                       float* __restrict__ ed_, int n){
    int i = blockIdx.x * 256 + threadIdx.x;
    if (i >= n) return;
    float s = 0.f, d = 0.f;
    #pragma unroll
    for (int k = 0; k < 20; k++) { float xv = x[i * 20 + k]; s += xv * va[k]; d += xv * vd[k]; }
    es[i] = s; ed_[i] = d;
}

// ---------------- mol L1 aggregate over raw x (6-dim half rows): 16 groups x 4 lanes ----------------
template<int OBITS>
__global__ void k_gather_x6(const int* __restrict__ rp, const int* __restrict__ col,
                            const float* __restrict__ w, const __half* __restrict__ xh,
                            const float* __restrict__ dinv, float* __restrict__ agg){
    int tid = threadIdx.x;
    int node = (blockIdx.x << 2) + (tid >> 6);
    int l = tid & 63, g = l >> 2, q = l & 3;
    unsigned pk = (unsigned)rp[node];
    int s0 = (int)(pk & ((1u << OBITS) - 1));
    int deg = (int)(pk >> OBITS);
    float dd = dinv[node];
    float2 acc = {0.f, 0.f};
    if (g == 0 && q < 3) {
        float2 f = __half22float2(*(const __half2*)&xh[node * 6 + 2 * q]);
        acc.x = dd * f.x; acc.y = dd * f.y;
    }
    for (int base = 0; base < deg; base += 16) {
        int s = base + g;
        int c = col[s0 + s];        // +16 slack allocated
        float ww = w[s0 + s];
        int u = (s < deg) ? c : node;
        float wv = (s < deg) ? ww : 0.f;
        if (q < 3) {
            float2 f = __half22float2(*(const __half2*)&xh[u * 6 + 2 * q]);
            acc.x += wv * f.x; acc.y += wv * f.y;
        }
    }
    #pragma unroll
    for (int m = 4; m <= 32; m <<= 1) {
        acc.x += __shfl_xor(acc.x, m, 64);
        acc.y += __shfl_xor(acc.y, m, 64);
    }
    if (g == 0 && q < 3)
        *(float2*)&agg[node * 6 + 2 * q] = make_float2(dd * acc.x, dd * acc.y);
}

// ---------------- GAT L1 aggregate over raw x (20-dim half rows): 8 groups x 8 lanes ----------------
template<int OBITS>
__global__ void k_gather_x20(const int* __restrict__ rp, const int* __restrict__ col,
                             const float* __restrict__ w, const __half* __restrict__ xh,
                             const float* __restrict__ es, const float* __restrict__ ed_,
                             float* __restrict__ agg){
    int tid = threadIdx.x;
    int node = (blockIdx.x << 2) + (tid >> 6);
    int l = tid & 63, g = l >> 3, q = l & 7;
    unsigned pk = (unsigned)rp[node];
    int s0 = (int)(pk & ((1u << OBITS) - 1));
    int deg = (int)(pk >> OBITS);
    float2 a0 = {0.f, 0.f}, a1 = {0.f, 0.f};
    float den = 0.f;
    if (g == 0) {
        float ws = __expf(leaky(es[node] + ed_[node]));
        den = ws;
        float2 f0 = __half22float2(*(const __half2*)&xh[node * 20 + 2 * q]);
        a0.x = ws * f0.x; a0.y = ws * f0.y;
        if (q < 2) {
            float2 f1 = __half22float2(*(const __half2*)&xh[node * 20 + 16 + 2 * q]);
            a1.x = ws * f1.x; a1.y = ws * f1.y;
        }
    }
    for (int base = 0; base < deg; base += 8) {
        int s = base + g;
        int c = col[s0 + s]; float ww = w[s0 + s];
        int u = (s < deg) ? c : node;
        float wv = (s < deg) ? ww : 0.f;
        float2 f0 = __half22float2(*(const __half2*)&xh[u * 20 + 2 * q]);
        a0.x += wv * f0.x; a0.y += wv * f0.y;
        if (q < 2) {
            float2 f1 = __half22float2(*(const __half2*)&xh[u * 20 + 16 + 2 * q]);
            a1.x += wv * f1.x; a1.y += wv * f1.y;
        }
        den += wv;
    }
    #pragma unroll
    for (int m = 8; m <= 32; m <<= 1) {
        a0.x += __shfl_xor(a0.x, m, 64); a0.y += __shfl_xor(a0.y, m, 64);
        a1.x += __shfl_xor(a1.x, m, 64); a1.y += __shfl_xor(a1.y, m, 64);
        den  += __shfl_xor(den, m, 64);
    }
    if (g == 0) {
        float inv = 1.f / den;
        *(float2*)&agg[node * 20 + 2 * q] = make_float2(a0.x * inv, a0.y * inv);
        if (q < 2)
            *(float2*)&agg[node * 20 + 16 + 2 * q] = make_float2(a1.x * inv, a1.y * inv);
    }
}

// ---------------- agg[n,D] @ W[D,64] + b (+relu) ----------------
template<int D, int RELU>
__global__ void k_xw_small(const float* __restrict__ x, const float* __restrict__ W,
                           const float* __restrict__ b, float* __restrict__ h, int n){
    __shared__ float Ws[D * 64];
    int tid = threadIdx.x;
    for (int k = tid; k < D * 64; k += 256) Ws[k] = W[k];
    __syncthreads();
    int node = blockIdx.x * 4 + (tid >> 6);
    int j = tid & 63;
    if (node >= n) return;
    float acc = b[j];
    #pragma unroll
    for (int k = 0; k < D; k++) acc += x[node * D + k] * Ws[k * 64 + j];
    if (RELU) acc = fmaxf(acc, 0.f);
    h[(size_t)node * 64 + j] = acc;
}

// ---------------- x[n,64] @ W[64,64] -> half (+ fused attention dots fp32) ----------------
template<int ATT>
__global__ void k_xw64h(const float* __restrict__ x, const float* __restrict__ W,
                        const float* __restrict__ as_, const float* __restrict__ ad_,
                        __half* __restrict__ hout, float* __restrict__ es,
                        float* __restrict__ ed_, int n){
    __shared__ float Ws[64 * 64];
    __shared__ float Xs[16 * 68];
    int tid = threadIdx.x;
    for (int k = tid * 4; k < 4096; k += 1024)
        *(float4*)&Ws[k] = *(const float4*)&W[k];
    int nd = tid >> 4, q = tid & 15;
    int node = blockIdx.x * 16 + nd;
    if (node < n)
        *(float4*)&Xs[nd * 68 + (q << 2)] = *(const float4*)&x[(size_t)node * 64 + (q << 2)];
    __syncthreads();
    if (node >= n) return;
    float4 acc = {0.f, 0.f, 0.f, 0.f};
    #pragma unroll 8
    for (int k = 0; k < 64; k++) {
        float xk = Xs[nd * 68 + k];
        float4 w4 = *(const float4*)&Ws[(k << 6) + (q << 2)];
        acc.x += xk * w4.x; acc.y += xk * w4.y; acc.z += xk * w4.z; acc.w += xk * w4.w;
    }
    union { __half2 h2[2]; float2 f2; } u;
    u.h2[0] = __floats2half2_rn(acc.x, acc.y);
    u.h2[1] = __floats2half2_rn(acc.z, acc.w);
    *(float2*)&hout[(size_t)node * 64 + (q << 2)] = u.f2;
    if (ATT) {
        int f = q << 2;
        float xa = acc.x * as_[f] + acc.y * as_[f + 1] + acc.z * as_[f + 2] + acc.w * as_[f + 3];
        float ya = acc.x * ad_[f] + acc.y * ad_[f + 1] + acc.z * ad_[f + 2] + acc.w * ad_[f + 3];
        #pragma unroll
        for (int m = 1; m < 16; m <<= 1) {
            xa += __shfl_xor(xa, m, 16);
            ya += __shfl_xor(ya, m, 16);
        }
        if (q == 0) { es[node] = xa; ed_[node] = ya; }
    }
}

// ---------------- layer-2 gather over half rows: 8 groups x 8 lanes, 16 B/lane ----------------
template<int GAT, int OBITS>
__global__ void k_gather64h(const int* __restrict__ rp, const int* __restrict__ col,
                            const float* __restrict__ w, const __half* __restrict__ hh,
                            const float* __restrict__ dinv, const float* __restrict__ es,
                            const float* __restrict__ ed_, const float* __restrict__ b,
                            float* __restrict__ out){
    int tid = threadIdx.x;
    int node = (blockIdx.x << 2) + (tid >> 6);
    int l = tid & 63, g = l >> 3, q = l & 7;
    unsigned pk = (unsigned)rp[node];
    int s0 = (int)(pk & ((1u << OBITS) - 1));
    int deg = (int)(pk >> OBITS);
    float acc[8] = {0.f,0.f,0.f,0.f,0.f,0.f,0.f,0.f};
    float den = 0.f;
    float selfw = GAT ? __expf(leaky(es[node] + ed_[node])) : dinv[node];
    if (g == 0) {
        H8 r; r.f4 = *(const float4*)&hh[(size_t)node * 64 + (q << 3)];
        #pragma unroll
        for (int i = 0; i < 4; i++) {
            float2 f = __half22float2(r.h2[i]);
            acc[2*i]     = selfw * f.x;
            acc[2*i + 1] = selfw * f.y;
        }
        den = selfw;
    }
    for (int base = 0; base < deg; base += 8) {
        int s = base + g;
        int c = col[s0 + s]; float ww = w[s0 + s];
        int u = (s < deg) ? c : node;
        float wv = (s < deg) ? ww : 0.f;
        H8 r; r.f4 = *(const float4*)&hh[(size_t)u * 64 + (q << 3)];
        #pragma unroll
        for (int i = 0; i < 4; i++) {
            float2 f = __half22float2(r.h2[i]);
            acc[2*i]     += wv * f.x;
            acc[2*i + 1] += wv * f.y;
        }
        if (GAT) den += wv;
    }
    #pragma unroll
    for (int m = 8; m <= 32; m <<= 1) {
        #pragma unroll
        for (int i = 0; i < 8; i++) acc[i] += __shfl_xor(acc[i], m, 64);
        if (GAT) den += __shfl_xor(den, m, 64);
    }
    if (g == 0) {
        float sc = GAT ? (1.f / den) : selfw;
        int f = q << 3;
        float4 v0, v1;
        v0.x = acc[0]*sc + b[f];     v0.y = acc[1]*sc + b[f+1];
        v0.z = acc[2]*sc + b[f+2];   v0.w = acc[3]*sc + b[f+3];
        v1.x = acc[4]*sc + b[f+4];   v1.y = acc[5]*sc + b[f+5];
        v1.z = acc[6]*sc + b[f+6];   v1.w = acc[7]*sc + b[f+7];
        *(float4*)&out[(size_t)node * 64 + f]     = v0;
        *(float4*)&out[(size_t)node * 64 + f + 4] = v1;
    }
}

// ---------------- mol pooling: segment-based (batch sorted) ----------------
__global__ void k_hist(const int* __restrict__ dst, int* __restrict__ cnt, int E){
    int e = blockIdx.x * 256 + threadIdx.x;
    if (e < E) atomicAdd(&cnt[dst[e]], 1);
}
__global__ void k_filli(int* __restrict__ p, int v, int n){
    int i = blockIdx.x * 256 + threadIdx.x;
    if (i < n) p[i] = v;
}
__global__ void k_gstart(const int* __restrict__ batch, int* __restrict__ gstart, int n){
    int i = blockIdx.x * 256 + threadIdx.x;
    if (i < n) atomicMin(&gstart[batch[i]], i);
}
__global__ void k_segpool(const int* __restrict__ gstart, const int* __restrict__ gcnt,
                          const float* __restrict__ x, float* __restrict__ gsum){
    int g = blockIdx.x, j = threadIdx.x;   // 64 threads
    int s = gstart[g], c = gcnt[g];
    float acc = 0.f;
    for (int i = 0; i < c; i++) acc += x[(size_t)(s + i) * 64 + j];
    gsum[g * 64 + j] = acc;
}

// ---------------- prot pooling ----------------
__global__ void k_pool_prot(const float* __restrict__ out, float* __restrict__ psum, int n){
    int j = threadIdx.x;
    float acc = 0.f;
    for (int i = blockIdx.x; i < n; i += gridDim.x) acc += out[i * 64 + j];
    atomicAdd(&psum[j], acc);
}

// ---------------- fused classifier ----------------
__global__ void k_cls(const float* __restrict__ gsum, const int* __restrict__ gcnt,
                      const float* __restrict__ psum, const float* __restrict__ W1,
                      const float* __restrict__ b1, const float* __restrict__ w2,
                      const float* __restrict__ b2, float* __restrict__ out){
    __shared__ float W1s[128 * 64];
    int tid = threadIdx.x;
    for (int k = tid; k < 128 * 64; k += 256) W1s[k] = W1[k];
    __syncthreads();
    int g = blockIdx.x * 4 + (tid >> 6);
    int j = tid & 63;
    float inv = 1.0f / fmaxf((float)gcnt[g], 1.0f);
    const float invp = 1.0f / (float)NP;
    float acc = b1[j];
    #pragma unroll 8
    for (int k = 0; k < 64; k++) acc += (gsum[g * 64 + k] * inv) * W1s[k * 64 + j];
    #pragma unroll 8
    for (int k = 0; k < 64; k++) acc += (psum[k] * invp) * W1s[(64 + k) * 64 + j];
    float v = fmaxf(acc, 0.f) * w2[j];
    #pragma unroll
    for (int off = 32; off > 0; off >>= 1) v += __shfl_down(v, off, 64);
    if (j == 0) out[g] = 1.0f / (1.0f + expf(-(v + b2[0])));
}

extern "C" void kernel_launch(void* const* d_in, const int* in_sizes, int n_in,
                              void* d_out, int out_size, void* d_ws, size_t ws_size,
                              hipStream_t stream) {
    const float* mol_x   = (const float*)d_in[0];
    const int*   mol_ei  = (const int*)d_in[1];
    const int*   mol_bat = (const int*)d_in[2];
    const float* prot_x  = (const float*)d_in[3];
    const int*   prot_ei = (const int*)d_in[4];
    const float* gcn_w1  = (const float*)d_in[5];
    const float* gcn_b1  = (const float*)d_in[6];
    const float* gcn_w2  = (const float*)d_in[7];
    const float* gcn_b2  = (const float*)d_in[8];
    const float* gat_w1  = (const float*)d_in[9];
    const float* gat_as1 = (const float*)d_in[10];
    const float* gat_ad1 = (const float*)d_in[11];
    const float* gat_b1  = (const float*)d_in[12];
    const float* gat_w2  = (const float*)d_in[13];
    const float* gat_as2 = (const float*)d_in[14];
    const float* gat_ad2 = (const float*)d_in[15];
    const float* gat_b2  = (const float*)d_in[16];
    const float* cls_w1  = (const float*)d_in[17];
    const float* cls_b1  = (const float*)d_in[18];
    const float* cls_w2  = (const float*)d_in[19];
    const float* cls_b2  = (const float*)d_in[20];
    float* out = (float*)d_out;

    float* ws_f = (float*)d_ws;

    // ---- persistent tail (beyond both phase regions) ----
    float* T      = ws_f + 16777216;
    float* gsum   = T;                       // 262,144
    int*   gcntI  = (int*)(T + 262144);      // 4,096
    float* psum   = T + 266240;              // 64
    int*   gstart = (int*)(T + 266304);      // 4,096
    float* va     = T + 270400;              // 32
    float* vd     = T + 270432;              // 32
    int*   coarse = (int*)(T + 270464);      // 512
    int*   cstart = (int*)(T + 270976);      // 513
    int*   cursor = (int*)(T + 271489);      // 512  -> tail ends T+272001

    // ---- mol-phase layout [0, 16777216) ----
    float*  h1     = ws_f;                               // [0, 8388608)
    float*  molout = ws_f;                               // overlay (h1 dead by then)
    __half* h2hM   = (__half*)(ws_f + 8388608);          // [8388608, 12582912)
    int*    molCOL = (int*)(ws_f + 12582912);            // EM+16 -> ends 13,107,216
    int*    molRP  = (int*)(ws_f + 13107216);            // NM+1  -> ends 13,238,289
    float*  dinvM  = ws_f + 13238304;                    // NM    -> ends 13,369,376
    float*  wM     = ws_f + 13369376;                    // EM+16 -> ends 13,893,680
    float*  aggM   = ws_f + 13893680;                    // NM*6  -> ends 14,680,112
    __half* x6h    = (__half*)(ws_f + 14680112);         // NM*6 halves -> ends 15,073,328
    unsigned* bufM = (unsigned*)(ws_f + 15073328);       // EM -> ends 15,597,616

    // ---- prot-phase layout [0, 16777216) (mol fully done first) ----
    float*  p       = ws_f;                              // NP*64 = 6,400,000
    float*  protout = ws_f;                              // overlay (p dead by then)
    __half* h2hP    = (__half*)(ws_f + 6400000);         // [6400000, 9600000)
    int*    protCOL = (int*)(ws_f + 9600000);            // EP+16 -> ends 11,200,016
    int*    protRP  = (int*)(ws_f + 11200016);           // NP+1
    float*  es      = ws_f + 11300020;                   // NP
    float*  ed_     = ws_f + 11400020;                   // NP
    float*  wP      = ws_f + 11500020;                   // EP+16 -> ends 13,100,036
    float*  aggP    = ws_f + 13100036;                   // NP*20 -> ends 15,100,036
    unsigned* bufP  = (unsigned*)aggP;                   // EP -> ends 14,700,036 (dead before aggP written)
    __half* x20h    = (__half*)(ws_f + 15100036);        // NP*20 halves -> ends 16,100,036

    const int KM = 512;   // NM/256
    const int KPb = 391;  // cdiv(NP,256)

    // ================= mol branch =================
    // bucketed CSR build
    hipMemsetAsync(coarse, 0, (size_t)KM * sizeof(int), stream);
    k_coarse_hist<2048><<<cdiv(EM,2048),256,0,stream>>>(mol_ei + EM, coarse, EM, KM);
    k_coarse_scan<<<1,512,0,stream>>>(coarse, cstart, cursor, KM, EM);
    k_part<2048,8><<<cdiv(EM,2048),256,0,stream>>>(mol_ei, cursor, bufM, EM, KM);
    k_fine<<<KM,256,0,stream>>>(bufM, cstart, molRP, molCOL, NM, KM);
    k_pack<20><<<cdiv(NM,256),256,0,stream>>>(molRP, NM);
    k_dinv<20><<<cdiv(NM,256),256,0,stream>>>(molRP, dinvM, NM);
    k_wgcn<<<cdiv(EM,256),256,0,stream>>>(molCOL, dinvM, wM, EM);
    k_x2h<<<cdiv(NM*DM,256),256,0,stream>>>(mol_x, x6h, NM*DM);
    // L1: aggregate x then transform
    k_gather_x6<20><<<NM/4,256,0,stream>>>(molRP, molCOL, wM, x6h, dinvM, aggM);
    k_xw_small<6,1><<<NM/4,256,0,stream>>>(aggM, gcn_w1, gcn_b1, h1, NM);
    // L2: transform to half, gather, write fp32
    k_xw64h<0><<<NM/16,256,0,stream>>>(h1, gcn_w2, nullptr, nullptr, h2hM, nullptr, nullptr, NM);
    k_gather64h<0,20><<<NM/4,256,0,stream>>>(molRP, molCOL, wM, h2hM, dinvM, nullptr, nullptr, gcn_b2, molout);
    // segment pooling
    k_filli<<<cdiv(NG,256),256,0,stream>>>(gstart, NM, NG);
    hipMemsetAsync(gcntI, 0, (size_t)NG * sizeof(int), stream);
    k_hist<<<cdiv(NM,256),256,0,stream>>>(mol_bat, gcntI, NM);
    k_gstart<<<cdiv(NM,256),256,0,stream>>>(mol_bat, gstart, NM);
    k_segpool<<<NG,64,0,stream>>>(gstart, gcntI, molout, gsum);

    // ================= prot branch =================
    // bucketed CSR build
    hipMemsetAsync(coarse, 0, (size_t)KPb * sizeof(int), stream);
    k_coarse_hist<4096><<<cdiv(EP,4096),256,0,stream>>>(prot_ei + EP, coarse, EP, KPb);
    k_coarse_scan<<<1,512,0,stream>>>(coarse, cstart, cursor, KPb, EP);
    k_part<4096,16><<<cdiv(EP,4096),256,0,stream>>>(prot_ei, cursor, bufP, EP, KPb);
    k_fine<<<KPb,256,0,stream>>>(bufP, cstart, protRP, protCOL, NP, KPb);
    k_pack<21><<<cdiv(NP,256),256,0,stream>>>(protRP, NP);
    // L1: es/ed from x directly, aggregate x, then transform
    k_x2h<<<cdiv(NP*DP,256),256,0,stream>>>(prot_x, x20h, NP*DP);
    k_va<<<1,64,0,stream>>>(gat_w1, gat_as1, gat_ad1, va, vd);
    k_esed<<<cdiv(NP,256),256,0,stream>>>(prot_x, va, vd, es, ed_, NP);
    k_wcsr<21><<<cdiv(NP*16,256),256,0,stream>>>(protRP, protCOL, es, ed_, wP, NP);
    k_gather_x20<21><<<NP/4,256,0,stream>>>(protRP, protCOL, wP, x20h, es, ed_, aggP);
    k_xw_small<20,1><<<NP/4,256,0,stream>>>(aggP, gat_w1, gat_b1, p, NP);
    // L2: transform to half (+att dots), gather
    k_xw64h<1><<<NP/16,256,0,stream>>>(p, gat_w2, gat_as2, gat_ad2, h2hP, es, ed_, NP);
    k_wcsr<21><<<cdiv(NP*16,256),256,0,stream>>>(protRP, protCOL, es, ed_, wP, NP);
    k_gather64h<1,21><<<NP/4,256,0,stream>>>(protRP, protCOL, wP, h2hP, nullptr, es, ed_, gat_b2, protout);
    hipMemsetAsync(psum, 0, 64 * sizeof(float), stream);
    k_pool_prot<<<256,64,0,stream>>>(protout, psum, NP);

    // ================= classifier =================
    k_cls<<<NG/4,256,0,stream>>>(gsum, gcntI, psum, cls_w1, cls_b1, cls_w2, cls_b2, out);
}

// Round 8
// 597.744 us; speedup vs baseline: 2.8843x; 1.1157x over previous
//
#include <hip/hip_runtime.h>
#include <hip/hip_fp16.h>

#define NM 131072   // mol nodes
#define EM 524288   // mol edges
#define NG 4096     // graphs
#define DM 6        // mol in dim
#define NP 100000   // prot nodes
#define EP 1600000  // prot edges
#define DP 20       // prot in dim

static inline int cdiv(int a, int b){ return (a + b - 1) / b; }

__device__ __forceinline__ float leaky(float x){ return x > 0.f ? x : 0.2f * x; }

union H8 { float4 f4; __half2 h2[4]; };

// ================= bucketed CSR build =================
// bucket = dst >> 8 (256 nodes/bucket). K_mol=512, K_prot=391.

template<int CHUNK>
__global__ void k_coarse_hist(const int* __restrict__ dst, int* __restrict__ coarse,
                              int E, int K){
    __shared__ int lh[512];
    int t = threadIdx.x;
    for (int i = t; i < K; i += 256) lh[i] = 0;
    __syncthreads();
    int base = blockIdx.x * CHUNK;
    int end = min(base + CHUNK, E);
    for (int e = base + t; e < end; e += 256)
        atomicAdd(&lh[dst[e] >> 8], 1);
    __syncthreads();
    for (int i = t; i < K; i += 256)
        if (lh[i]) atomicAdd(&coarse[i], lh[i]);
}

__global__ void k_coarse_scan(const int* __restrict__ coarse, int* __restrict__ cstart,
                              int* __restrict__ cursor, int K, int E){
    int t = threadIdx.x, lane = t & 63, wid = t >> 6;
    int v0 = (t < K) ? coarse[t] : 0;
    int v = v0;
    #pragma unroll
    for (int off = 1; off < 64; off <<= 1) {
        int x = __shfl_up(v, off, 64);
        if (lane >= off) v += x;
    }
    __shared__ int ws[8];
    if (lane == 63) ws[wid] = v;
    __syncthreads();
    int add = 0;
    for (int w = 0; w < wid; w++) add += ws[w];
    int excl = v + add - v0;
    if (t < K) { cstart[t] = excl; cursor[t] = excl; }
    if (t == K - 1) cstart[K] = excl + v0;   // == E
}

template<int CHUNK, int EPT>
__global__ void k_part(const int* __restrict__ ei, int* __restrict__ cursor,
                       unsigned* __restrict__ buf, int E, int K){
    __shared__ int lh[512];
    __shared__ int lbase[512];
    int t = threadIdx.x;
    for (int i = t; i < K; i += 256) lh[i] = 0;
    __syncthreads();
    int base = blockIdx.x * CHUNK;
    int end = min(base + CHUNK, E);
    unsigned pay[EPT]; int bslot[EPT];
    int cnt = 0;
    for (int e = base + t; e < end; e += 256) {
        int u = ei[e], v = ei[E + e];
        int b = v >> 8;
        int ls = atomicAdd(&lh[b], 1);
        pay[cnt] = ((unsigned)(v & 255) << 24) | (unsigned)u;
        bslot[cnt] = (b << 13) | ls;
        cnt++;
    }
    __syncthreads();
    for (int i = t; i < K; i += 256)
        lbase[i] = lh[i] ? atomicAdd(&cursor[i], lh[i]) : 0;
    __syncthreads();
    for (int j = 0; j < cnt; j++) {
        int b = bslot[j] >> 13, ls = bslot[j] & 8191;
        buf[lbase[b] + ls] = pay[j];
    }
}

__global__ void k_fine(const unsigned* __restrict__ buf, const int* __restrict__ cstart,
                       int* __restrict__ rp, int* __restrict__ col, int n, int K){
    int k = blockIdx.x, t = threadIdx.x;
    int start = cstart[k], end = cstart[k + 1];
    __shared__ int cnt[256];
    __shared__ int cur[256];
    cnt[t] = 0;
    __syncthreads();
    for (int p = start + t; p < end; p += 256)
        atomicAdd(&cnt[buf[p] >> 24], 1);
    __syncthreads();
    int v0 = cnt[t];
    int lane = t & 63, wid = t >> 6;
    int v = v0;
    #pragma unroll
    for (int off = 1; off < 64; off <<= 1) {
        int x = __shfl_up(v, off, 64);
        if (lane >= off) v += x;
    }
    __shared__ int ws[4];
    if (lane == 63) ws[wid] = v;
    __syncthreads();
    int add = 0;
    for (int w = 0; w < wid; w++) add += ws[w];
    int excl = v + add - v0;
    int ofs = start + excl;
    cur[t] = ofs;
    int idx = (k << 8) + t;
    if (idx <= n) rp[idx] = ofs;
    if (k == K - 1 && t == 255) rp[n] = end;
    __syncthreads();
    for (int p = start + t; p < end; p += 256) {
        unsigned pk = buf[p];
        int slot = atomicAdd(&cur[pk >> 24], 1);
        col[slot] = (int)(pk & 0xFFFFFFu);
    }
}

// in-place pack: rp[i] = start | (deg << OBITS)
template<int OBITS>
__global__ void k_pack(int* __restrict__ rp, int n){
    int i = blockIdx.x * 256 + threadIdx.x;
    if (i < n) {
        const unsigned M = (1u << OBITS) - 1;
        unsigned lo = ((unsigned)rp[i]) & M;
        unsigned hi = ((unsigned)rp[i + 1]) & M;
        rp[i] = (int)(lo | ((hi - lo) << OBITS));
    }
}

template<int OBITS>
__global__ void k_dinv(const int* __restrict__ rp, float* __restrict__ dinv, int n){
    int i = blockIdx.x * 256 + threadIdx.x;
    if (i < n) dinv[i] = rsqrtf((float)(((unsigned)rp[i] >> OBITS) + 1));
}

__global__ void k_wgcn(const int* __restrict__ col, const float* __restrict__ dinv,
                       float* __restrict__ w, int E){
    int p = blockIdx.x * 256 + threadIdx.x;
    if (p < E) w[p] = dinv[col[p]];
}

template<int OBITS>
__global__ void k_wcsr(const int* __restrict__ rp, const int* __restrict__ col,
                       const float* __restrict__ es, const float* __restrict__ ed_,
                       float* __restrict__ w, int n){
    int t = blockIdx.x * 256 + threadIdx.x;
    int node = t >> 4, q = t & 15;
    unsigned pk = (unsigned)rp[node];
    int s0 = (int)(pk & ((1u << OBITS) - 1));
    int deg = (int)(pk >> OBITS);
    float edv = ed_[node];
    for (int s = q; s < deg; s += 16) {
        int u = col[s0 + s];
        w[s0 + s] = __expf(leaky(es[u] + edv));
    }
}

__global__ void k_x2h(const float* __restrict__ x, __half* __restrict__ xh, int n){
    int i = blockIdx.x * 256 + threadIdx.x;
    if (i < n) xh[i] = __float2half(x[i]);
}

__global__ void k_va(const float* __restrict__ W, const float* __restrict__ as_,
                     const float* __restrict__ ad_, float* __restrict__ va,
                     float* __restrict__ vd){
    int t = threadIdx.x;
    if (t < 20) {
        float s = 0.f;
        for (int j = 0; j < 64; j++) s += W[t * 64 + j] * as_[j];
        va[t] = s;
    } else if (t >= 32 && t < 52) {
        int k = t - 32;
        float s = 0.f;
        for (int j = 0; j < 64; j++) s += W[k * 64 + j] * ad_[j];
        vd[k] = s;
    }
}

__global__ void k_esed(const float* __restrict__ x, const float* __restrict__ va,
                       const float* __restrict__ vd, float* __restrict__ es,
                       float* __restrict__ ed_, int n){
    int i = blockIdx.x * 256 + threadIdx.x;
    if (i >= n) return;
    float s = 0.f, d = 0.f;
    #pragma unroll
    for (int k = 0; k < 20; k++) { float xv = x[i * 20 + k]; s += xv * va[k]; d += xv * vd[k]; }
    es[i] = s; ed_[i] = d;
}

// ---------------- mol L1 aggregate over raw x (6-dim half rows) ----------------
template<int OBITS>
__global__ void k_gather_x6(const int* __restrict__ rp, const int* __restrict__ col,
                            const float* __restrict__ w, const __half* __restrict__ xh,
                            const float* __restrict__ dinv, float* __restrict__ agg){
    int tid = threadIdx.x;
    int node = (blockIdx.x << 2) + (tid >> 6);
    int l = tid & 63, g = l >> 2, q = l & 3;
    unsigned pk = (unsigned)rp[node];
    int s0 = (int)(pk & ((1u << OBITS) - 1));
    int deg = (int)(pk >> OBITS);
    float dd = dinv[node];
    float2 acc = {0.f, 0.f};
    if (g == 0 && q < 3) {
        float2 f = __half22float2(*(const __half2*)&xh[node * 6 + 2 * q]);
        acc.x = dd * f.x; acc.y = dd * f.y;
    }
    for (int base = 0; base < deg; base += 16) {
        int s = base + g;
        int c = col[s0 + s];
        float ww = w[s0 + s];
        int u = (s < deg) ? c : node;
        float wv = (s < deg) ? ww : 0.f;
        if (q < 3) {
            float2 f = __half22float2(*(const __half2*)&xh[u * 6 + 2 * q]);
            acc.x += wv * f.x; acc.y += wv * f.y;
        }
    }
    #pragma unroll
    for (int m = 4; m <= 32; m <<= 1) {
        acc.x += __shfl_xor(acc.x, m, 64);
        acc.y += __shfl_xor(acc.y, m, 64);
    }
    if (g == 0 && q < 3)
        *(float2*)&agg[node * 6 + 2 * q] = make_float2(dd * acc.x, dd * acc.y);
}

// ---------------- GAT L1 aggregate over raw x (20-dim half rows) ----------------
template<int OBITS>
__global__ void k_gather_x20(const int* __restrict__ rp, const int* __restrict__ col,
                             const float* __restrict__ w, const __half* __restrict__ xh,
                             const float* __restrict__ es, const float* __restrict__ ed_,
                             float* __restrict__ agg){
    int tid = threadIdx.x;
    int node = (blockIdx.x << 2) + (tid >> 6);
    int l = tid & 63, g = l >> 3, q = l & 7;
    unsigned pk = (unsigned)rp[node];
    int s0 = (int)(pk & ((1u << OBITS) - 1));
    int deg = (int)(pk >> OBITS);
    float2 a0 = {0.f, 0.f}, a1 = {0.f, 0.f};
    float den = 0.f;
    if (g == 0) {
        float ws = __expf(leaky(es[node] + ed_[node]));
        den = ws;
        float2 f0 = __half22float2(*(const __half2*)&xh[node * 20 + 2 * q]);
        a0.x = ws * f0.x; a0.y = ws * f0.y;
        if (q < 2) {
            float2 f1 = __half22float2(*(const __half2*)&xh[node * 20 + 16 + 2 * q]);
            a1.x = ws * f1.x; a1.y = ws * f1.y;
        }
    }
    for (int base = 0; base < deg; base += 8) {
        int s = base + g;
        int c = col[s0 + s]; float ww = w[s0 + s];
        int u = (s < deg) ? c : node;
        float wv = (s < deg) ? ww : 0.f;
        float2 f0 = __half22float2(*(const __half2*)&xh[u * 20 + 2 * q]);
        a0.x += wv * f0.x; a0.y += wv * f0.y;
        if (q < 2) {
            float2 f1 = __half22float2(*(const __half2*)&xh[u * 20 + 16 + 2 * q]);
            a1.x += wv * f1.x; a1.y += wv * f1.y;
        }
        den += wv;
    }
    #pragma unroll
    for (int m = 8; m <= 32; m <<= 1) {
        a0.x += __shfl_xor(a0.x, m, 64); a0.y += __shfl_xor(a0.y, m, 64);
        a1.x += __shfl_xor(a1.x, m, 64); a1.y += __shfl_xor(a1.y, m, 64);
        den  += __shfl_xor(den, m, 64);
    }
    if (g == 0) {
        float inv = 1.f / den;
        *(float2*)&agg[node * 20 + 2 * q] = make_float2(a0.x * inv, a0.y * inv);
        if (q < 2)
            *(float2*)&agg[node * 20 + 16 + 2 * q] = make_float2(a1.x * inv, a1.y * inv);
    }
}

// ---------------- agg[n,D] @ W[D,64] + b (+relu) ----------------
template<int D, int RELU>
__global__ void k_xw_small(const float* __restrict__ x, const float* __restrict__ W,
                           const float* __restrict__ b, float* __restrict__ h, int n){
    __shared__ float Ws[D * 64];
    int tid = threadIdx.x;
    for (int k = tid; k < D * 64; k += 256) Ws[k] = W[k];
    __syncthreads();
    int node = blockIdx.x * 4 + (tid >> 6);
    int j = tid & 63;
    if (node >= n) return;
    float acc = b[j];
    #pragma unroll
    for (int k = 0; k < D; k++) acc += x[node * D + k] * Ws[k * 64 + j];
    if (RELU) acc = fmaxf(acc, 0.f);
    h[(size_t)node * 64 + j] = acc;
}

// ---------------- x[n,64] @ W[64,64] -> half (+ fused attention dots) ----------------
template<int ATT>
__global__ void k_xw64h(const float* __restrict__ x, const float* __restrict__ W,
                        const float* __restrict__ as_, const float* __restrict__ ad_,
                        __half* __restrict__ hout, float* __restrict__ es,
                        float* __restrict__ ed_, int n){
    __shared__ float Ws[64 * 64];
    __shared__ float Xs[16 * 68];
    int tid = threadIdx.x;
    for (int k = tid * 4; k < 4096; k += 1024)
        *(float4*)&Ws[k] = *(const float4*)&W[k];
    int nd = tid >> 4, q = tid & 15;
    int node = blockIdx.x * 16 + nd;
    if (node < n)
        *(float4*)&Xs[nd * 68 + (q << 2)] = *(const float4*)&x[(size_t)node * 64 + (q << 2)];
    __syncthreads();
    if (node >= n) return;
    float4 acc = {0.f, 0.f, 0.f, 0.f};
    #pragma unroll 8
    for (int k = 0; k < 64; k++) {
        float xk = Xs[nd * 68 + k];
        float4 w4 = *(const float4*)&Ws[(k << 6) + (q << 2)];
        acc.x += xk * w4.x; acc.y += xk * w4.y; acc.z += xk * w4.z; acc.w += xk * w4.w;
    }
    union { __half2 h2[2]; float2 f2; } u;
    u.h2[0] = __floats2half2_rn(acc.x, acc.y);
    u.h2[1] = __floats2half2_rn(acc.z, acc.w);
    *(float2*)&hout[(size_t)node * 64 + (q << 2)] = u.f2;
    if (ATT) {
        int f = q << 2;
        float xa = acc.x * as_[f] + acc.y * as_[f + 1] + acc.z * as_[f + 2] + acc.w * as_[f + 3];
        float ya = acc.x * ad_[f] + acc.y * ad_[f + 1] + acc.z * ad_[f + 2] + acc.w * ad_[f + 3];
        #pragma unroll
        for (int m = 1; m < 16; m <<= 1) {
            xa += __shfl_xor(xa, m, 16);
            ya += __shfl_xor(ya, m, 16);
        }
        if (q == 0) { es[node] = xa; ed_[node] = ya; }
    }
}

// ---------------- layer-2 gather over half rows ----------------
template<int GAT, int OBITS>
__global__ void k_gather64h(const int* __restrict__ rp, const int* __restrict__ col,
                            const float* __restrict__ w, const __half* __restrict__ hh,
                            const float* __restrict__ dinv, const float* __restrict__ es,
                            const float* __restrict__ ed_, const float* __restrict__ b,
                            float* __restrict__ out){
    int tid = threadIdx.x;
    int node = (blockIdx.x << 2) + (tid >> 6);
    int l = tid & 63, g = l >> 3, q = l & 7;
    unsigned pk = (unsigned)rp[node];
    int s0 = (int)(pk & ((1u << OBITS) - 1));
    int deg = (int)(pk >> OBITS);
    float acc[8] = {0.f,0.f,0.f,0.f,0.f,0.f,0.f,0.f};
    float den = 0.f;
    float selfw = GAT ? __expf(leaky(es[node] + ed_[node])) : dinv[node];
    if (g == 0) {
        H8 r; r.f4 = *(const float4*)&hh[(size_t)node * 64 + (q << 3)];
        #pragma unroll
        for (int i = 0; i < 4; i++) {
            float2 f = __half22float2(r.h2[i]);
            acc[2*i]     = selfw * f.x;
            acc[2*i + 1] = selfw * f.y;
        }
        den = selfw;
    }
    for (int base = 0; base < deg; base += 8) {
        int s = base + g;
        int c = col[s0 + s]; float ww = w[s0 + s];
        int u = (s < deg) ? c : node;
        float wv = (s < deg) ? ww : 0.f;
        H8 r; r.f4 = *(const float4*)&hh[(size_t)u * 64 + (q << 3)];
        #pragma unroll
        for (int i = 0; i < 4; i++) {
            float2 f = __half22float2(r.h2[i]);
            acc[2*i]     += wv * f.x;
            acc[2*i + 1] += wv * f.y;
        }
        if (GAT) den += wv;
    }
    #pragma unroll
    for (int m = 8; m <= 32; m <<= 1) {
        #pragma unroll
        for (int i = 0; i < 8; i++) acc[i] += __shfl_xor(acc[i], m, 64);
        if (GAT) den += __shfl_xor(den, m, 64);
    }
    if (g == 0) {
        float sc = GAT ? (1.f / den) : selfw;
        int f = q << 3;
        float4 v0, v1;
        v0.x = acc[0]*sc + b[f];     v0.y = acc[1]*sc + b[f+1];
        v0.z = acc[2]*sc + b[f+2];   v0.w = acc[3]*sc + b[f+3];
        v1.x = acc[4]*sc + b[f+4];   v1.y = acc[5]*sc + b[f+5];
        v1.z = acc[6]*sc + b[f+6];   v1.w = acc[7]*sc + b[f+7];
        *(float4*)&out[(size_t)node * 64 + f]     = v0;
        *(float4*)&out[(size_t)node * 64 + f + 4] = v1;
    }
}

// ---------------- mol pooling: segment-based (batch sorted) ----------------
__global__ void k_hist(const int* __restrict__ dst, int* __restrict__ cnt, int E){
    int e = blockIdx.x * 256 + threadIdx.x;
    if (e < E) atomicAdd(&cnt[dst[e]], 1);
}
__global__ void k_filli(int* __restrict__ p, int v, int n){
    int i = blockIdx.x * 256 + threadIdx.x;
    if (i < n) p[i] = v;
}
__global__ void k_gstart(const int* __restrict__ batch, int* __restrict__ gstart, int n){
    int i = blockIdx.x * 256 + threadIdx.x;
    if (i < n) atomicMin(&gstart[batch[i]], i);
}
// 64 threads: 4 row-groups x 16 lanes, float4 loads, 4 rows in flight
__global__ void k_segpool(const int* __restrict__ gstart, const int* __restrict__ gcnt,
                          const float* __restrict__ x, float* __restrict__ gsum){
    int gph = blockIdx.x, t = threadIdx.x;
    int rg = t >> 4, q = t & 15;
    int s = gstart[gph], c = gcnt[gph];
    float4 a = {0.f, 0.f, 0.f, 0.f};
    for (int i = rg; i < c; i += 4) {
        float4 v = *(const float4*)&x[(size_t)(s + i) * 64 + (q << 2)];
        a.x += v.x; a.y += v.y; a.z += v.z; a.w += v.w;
    }
    #pragma unroll
    for (int m = 16; m <= 32; m <<= 1) {
        a.x += __shfl_xor(a.x, m, 64);
        a.y += __shfl_xor(a.y, m, 64);
        a.z += __shfl_xor(a.z, m, 64);
        a.w += __shfl_xor(a.w, m, 64);
    }
    if (rg == 0) *(float4*)&gsum[gph * 64 + (q << 2)] = a;
}

// ---------------- prot pooling: 1024 blocks x 256 threads, float4 grid-stride ----------------
__global__ void k_pool_prot(const float* __restrict__ x, float* __restrict__ psum, int n){
    __shared__ float red[4][64];
    int t = threadIdx.x, lane = t & 63, wv = t >> 6;
    const float4* x4 = (const float4*)x;
    int total = n * 16;   // float4 count
    float4 a = {0.f, 0.f, 0.f, 0.f};
    for (int i = blockIdx.x * 256 + t; i < total; i += gridDim.x * 256) {
        float4 v = x4[i];
        a.x += v.x; a.y += v.y; a.z += v.z; a.w += v.w;
    }
    // lanes t, t^16, t^32, t^48 share the same feature quad (stride multiple of 64 floats)
    #pragma unroll
    for (int m = 16; m <= 32; m <<= 1) {
        a.x += __shfl_xor(a.x, m, 64);
        a.y += __shfl_xor(a.y, m, 64);
        a.z += __shfl_xor(a.z, m, 64);
        a.w += __shfl_xor(a.w, m, 64);
    }
    if (lane < 16) *(float4*)&red[wv][lane << 2] = a;
    __syncthreads();
    if (t < 64) {
        float s = red[0][t] + red[1][t] + red[2][t] + red[3][t];
        atomicAdd(&psum[t], s);
    }
}

// ---------------- fused classifier ----------------
__global__ void k_cls(const float* __restrict__ gsum, const int* __restrict__ gcnt,
                      const float* __restrict__ psum, const float* __restrict__ W1,
                      const float* __restrict__ b1, const float* __restrict__ w2,
                      const float* __restrict__ b2, float* __restrict__ out){
    __shared__ float W1s[128 * 64];
    int tid = threadIdx.x;
    for (int k = tid; k < 128 * 64; k += 256) W1s[k] = W1[k];
    __syncthreads();
    int g = blockIdx.x * 4 + (tid >> 6);
    int j = tid & 63;
    float inv = 1.0f / fmaxf((float)gcnt[g], 1.0f);
    const float invp = 1.0f / (float)NP;
    float acc = b1[j];
    #pragma unroll 8
    for (int k = 0; k < 64; k++) acc += (gsum[g * 64 + k] * inv) * W1s[k * 64 + j];
    #pragma unroll 8
    for (int k = 0; k < 64; k++) acc += (psum[k] * invp) * W1s[(64 + k) * 64 + j];
    float v = fmaxf(acc, 0.f) * w2[j];
    #pragma unroll
    for (int off = 32; off > 0; off >>= 1) v += __shfl_down(v, off, 64);
    if (j == 0) out[g] = 1.0f / (1.0f + expf(-(v + b2[0])));
}

extern "C" void kernel_launch(void* const* d_in, const int* in_sizes, int n_in,
                              void* d_out, int out_size, void* d_ws, size_t ws_size,
                              hipStream_t stream) {
    const float* mol_x   = (const float*)d_in[0];
    const int*   mol_ei  = (const int*)d_in[1];
    const int*   mol_bat = (const int*)d_in[2];
    const float* prot_x  = (const float*)d_in[3];
    const int*   prot_ei = (const int*)d_in[4];
    const float* gcn_w1  = (const float*)d_in[5];
    const float* gcn_b1  = (const float*)d_in[6];
    const float* gcn_w2  = (const float*)d_in[7];
    const float* gcn_b2  = (const float*)d_in[8];
    const float* gat_w1  = (const float*)d_in[9];
    const float* gat_as1 = (const float*)d_in[10];
    const float* gat_ad1 = (const float*)d_in[11];
    const float* gat_b1  = (const float*)d_in[12];
    const float* gat_w2  = (const float*)d_in[13];
    const float* gat_as2 = (const float*)d_in[14];
    const float* gat_ad2 = (const float*)d_in[15];
    const float* gat_b2  = (const float*)d_in[16];
    const float* cls_w1  = (const float*)d_in[17];
    const float* cls_b1  = (const float*)d_in[18];
    const float* cls_w2  = (const float*)d_in[19];
    const float* cls_b2  = (const float*)d_in[20];
    float* out = (float*)d_out;

    float* ws_f = (float*)d_ws;

    // ---- persistent tail (beyond both phase regions) ----
    float* T      = ws_f + 16777216;
    float* gsum   = T;                       // 262,144
    int*   gcntI  = (int*)(T + 262144);      // 4,096
    float* psum   = T + 266240;              // 64
    int*   gstart = (int*)(T + 266304);      // 4,096
    float* va     = T + 270400;              // 32
    float* vd     = T + 270432;              // 32
    int*   coarse = (int*)(T + 270464);      // 512
    int*   cstart = (int*)(T + 270976);      // 513
    int*   cursor = (int*)(T + 271489);      // 512

    // ---- mol-phase layout [0, 16777216) ----
    float*  h1     = ws_f;                               // [0, 8388608)
    float*  molout = ws_f;                               // overlay (h1 dead by then)
    __half* h2hM   = (__half*)(ws_f + 8388608);          // [8388608, 12582912)
    int*    molCOL = (int*)(ws_f + 12582912);            // EM+16
    int*    molRP  = (int*)(ws_f + 13107216);            // NM+1
    float*  dinvM  = ws_f + 13238304;                    // NM
    float*  wM     = ws_f + 13369376;                    // EM+16
    float*  aggM   = ws_f + 13893680;                    // NM*6
    __half* x6h    = (__half*)(ws_f + 14680112);         // NM*6 halves
    unsigned* bufM = (unsigned*)(ws_f + 15073328);       // EM

    // ---- prot-phase layout [0, 16777216) (mol fully done first) ----
    float*  p       = ws_f;                              // NP*64
    float*  protout = ws_f;                              // overlay
    __half* h2hP    = (__half*)(ws_f + 6400000);         // [6400000, 9600000)
    int*    protCOL = (int*)(ws_f + 9600000);            // EP+16
    int*    protRP  = (int*)(ws_f + 11200016);           // NP+1
    float*  es      = ws_f + 11300020;                   // NP
    float*  ed_     = ws_f + 11400020;                   // NP
    float*  wP      = ws_f + 11500020;                   // EP+16
    float*  aggP    = ws_f + 13100036;                   // NP*20
    unsigned* bufP  = (unsigned*)aggP;                   // EP (dead before aggP written)
    __half* x20h    = (__half*)(ws_f + 15100036);        // NP*20 halves

    const int KM = 512;   // NM/256
    const int KPb = 391;  // cdiv(NP,256)

    // ================= mol branch =================
    hipMemsetAsync(coarse, 0, (size_t)KM * sizeof(int), stream);
    k_coarse_hist<2048><<<cdiv(EM,2048),256,0,stream>>>(mol_ei + EM, coarse, EM, KM);
    k_coarse_scan<<<1,512,0,stream>>>(coarse, cstart, cursor, KM, EM);
    k_part<2048,8><<<cdiv(EM,2048),256,0,stream>>>(mol_ei, cursor, bufM, EM, KM);
    k_fine<<<KM,256,0,stream>>>(bufM, cstart, molRP, molCOL, NM, KM);
    k_pack<20><<<cdiv(NM,256),256,0,stream>>>(molRP, NM);
    k_dinv<20><<<cdiv(NM,256),256,0,stream>>>(molRP, dinvM, NM);
    k_wgcn<<<cdiv(EM,256),256,0,stream>>>(molCOL, dinvM, wM, EM);
    k_x2h<<<cdiv(NM*DM,256),256,0,stream>>>(mol_x, x6h, NM*DM);
    k_gather_x6<20><<<NM/4,256,0,stream>>>(molRP, molCOL, wM, x6h, dinvM, aggM);
    k_xw_small<6,1><<<NM/4,256,0,stream>>>(aggM, gcn_w1, gcn_b1, h1, NM);
    k_xw64h<0><<<NM/16,256,0,stream>>>(h1, gcn_w2, nullptr, nullptr, h2hM, nullptr, nullptr, NM);
    k_gather64h<0,20><<<NM/4,256,0,stream>>>(molRP, molCOL, wM, h2hM, dinvM, nullptr, nullptr, gcn_b2, molout);
    k_filli<<<cdiv(NG,256),256,0,stream>>>(gstart, NM, NG);
    hipMemsetAsync(gcntI, 0, (size_t)NG * sizeof(int), stream);
    k_hist<<<cdiv(NM,256),256,0,stream>>>(mol_bat, gcntI, NM);
    k_gstart<<<cdiv(NM,256),256,0,stream>>>(mol_bat, gstart, NM);
    k_segpool<<<NG,64,0,stream>>>(gstart, gcntI, molout, gsum);

    // ================= prot branch =================
    hipMemsetAsync(coarse, 0, (size_t)KPb * sizeof(int), stream);
    k_coarse_hist<4096><<<cdiv(EP,4096),256,0,stream>>>(prot_ei + EP, coarse, EP, KPb);
    k_coarse_scan<<<1,512,0,stream>>>(coarse, cstart, cursor, KPb, EP);
    k_part<4096,16><<<cdiv(EP,4096),256,0,stream>>>(prot_ei, cursor, bufP, EP, KPb);
    k_fine<<<KPb,256,0,stream>>>(bufP, cstart, protRP, protCOL, NP, KPb);
    k_pack<21><<<cdiv(NP,256),256,0,stream>>>(protRP, NP);
    k_x2h<<<cdiv(NP*DP,256),256,0,stream>>>(prot_x, x20h, NP*DP);
    k_va<<<1,64,0,stream>>>(gat_w1, gat_as1, gat_ad1, va, vd);
    k_esed<<<cdiv(NP,256),256,0,stream>>>(prot_x, va, vd, es, ed_, NP);
    k_wcsr<21><<<cdiv(NP*16,256),256,0,stream>>>(protRP, protCOL, es, ed_, wP, NP);
    k_gather_x20<21><<<NP/4,256,0,stream>>>(protRP, protCOL, wP, x20h, es, ed_, aggP);
    k_xw_small<20,1><<<NP/4,256,0,stream>>>(aggP, gat_w1, gat_b1, p, NP);
    k_xw64h<1><<<NP/16,256,0,stream>>>(p, gat_w2, gat_as2, gat_ad2, h2hP, es, ed_, NP);
    k_wcsr<21><<<cdiv(NP*16,256),256,0,stream>>>(protRP, protCOL, es, ed_, wP, NP);
    k_gather64h<1,21><<<NP/4,256,0,stream>>>(protRP, protCOL, wP, h2hP, nullptr, es, ed_, gat_b2, protout);
    hipMemsetAsync(psum, 0, 64 * sizeof(float), stream);
    k_pool_prot<<<1024,256,0,stream>>>(protout, psum, NP);

    // ================= classifier =================
    k_cls<<<NG/4,256,0,stream>>>(gsum, gcntI, psum, cls_w1, cls_b1, cls_w2, cls_b2, out);
}